// Round 2
// baseline (413.314 us; speedup 1.0000x reference)
//
#include <hip/hip_runtime.h>

// B=2 S=8192 E=1024 H=16 D=64 CHUNK=128 NC=64

using h16   = _Float16;
using h16x8 = __attribute__((ext_vector_type(8))) _Float16;
using h16x4 = __attribute__((ext_vector_type(4))) _Float16;
using f32x4 = __attribute__((ext_vector_type(4))) float;

#define MFMA16(a,b,c) __builtin_amdgcn_mfma_f32_16x16x32_f16(a,b,c,0,0,0)

#define GLOAD16(gp, lp) __builtin_amdgcn_global_load_lds( \
    (const __attribute__((address_space(1))) void*)(gp),  \
    (__attribute__((address_space(3))) void*)(lp), 16, 0, 0)

// ---------------- fp32 -> fp16 convert (8 elems/thread) ----------------
__global__ __launch_bounds__(256) void k_cvt(const float* __restrict__ s,
                                             h16* __restrict__ d, int n) {
  int i = (blockIdx.x * 256 + threadIdx.x) * 8;
  if (i >= n) return;
  float4 a = *(const float4*)(s + i);
  float4 b = *(const float4*)(s + i + 4);
  h16x8 o;
  o[0]=(h16)a.x; o[1]=(h16)a.y; o[2]=(h16)a.z; o[3]=(h16)a.w;
  o[4]=(h16)b.x; o[5]=(h16)b.y; o[6]=(h16)b.z; o[7]=(h16)b.w;
  *(h16x8*)(d + i) = o;
}

// ---------------- QKV GEMM (M=16384, N=3072, K=1024) + RoPE ----------------
// 256x256 tile, 8 waves (2x4 of 128x64), BK=32, 4-deep gload_lds ring,
// counted vmcnt, setprio around MFMA cluster, XCD swizzle.
__global__ __launch_bounds__(512, 2) void k_qkv(
    const h16* __restrict__ xh, const h16* __restrict__ w3,
    const float* __restrict__ fc,
    h16* __restrict__ qh, h16* __restrict__ kh, h16* __restrict__ vh)
{
  extern __shared__ __align__(16) char smem[];   // 128 KiB
  h16* lA = (h16*)smem;                          // 4 x [256][32] fp16
  h16* lB = (h16*)(smem + 65536);
  const int tid = threadIdx.x;
  const int w = tid >> 6, l = tid & 63;
  const int orig = blockIdx.y * gridDim.x + blockIdx.x;
  const int cpx = (gridDim.x * gridDim.y) >> 3;
  const int swz = (orig & 7) * cpx + (orig >> 3);
  const int m0 = (swz & 63) << 8;
  const int n0 = (swz >> 6) << 8;
  const int wr = w >> 2, wc = w & 3;
  const h16* At = xh + (size_t)m0 * 1024;
  const h16* Bt = w3 + (size_t)n0 * 1024;
  const int srow0 = w*16 + (l >> 2);   // staging row (+c*128)
  const int sl0 = l & 3;               // physical 16B slot this lane fills

  auto stage = [&](int kt) {
    const int kb = (kt & 3) * 16384;
    #pragma unroll
    for (int c = 0; c < 2; c++) {
      int row = c*128 + srow0;
      int sl = sl0 ^ ((row >> 1) & 3);           // pre-swizzled source
      GLOAD16(At + (size_t)row*1024 + kt*32 + sl*8, (char*)lA + kb + c*8192 + w*1024);
      GLOAD16(Bt + (size_t)row*1024 + kt*32 + sl*8, (char*)lB + kb + c*8192 + w*1024);
    }
  };

  f32x4 acc[8][4] = {};
  stage(0); stage(1); stage(2);
  asm volatile("s_waitcnt vmcnt(8)\ns_barrier" ::: "memory");

  for (int t = 0; t < 32; ++t) {
    if (t < 29) stage(t + 3);
    const h16* bufA = lA + (t & 3) * 8192;
    const h16* bufB = lB + (t & 3) * 8192;
    h16x8 af[8], bf[4];
    #pragma unroll
    for (int mf = 0; mf < 8; mf++) {
      int row = wr*128 + mf*16 + (l & 15);
      int sl = (l >> 4) ^ ((row >> 1) & 3);
      af[mf] = *(const h16x8*)(bufA + row*32 + sl*8);
    }
    #pragma unroll
    for (int nf = 0; nf < 4; nf++) {
      int row = wc*64 + nf*16 + (l & 15);
      int sl = (l >> 4) ^ ((row >> 1) & 3);
      bf[nf] = *(const h16x8*)(bufB + row*32 + sl*8);
    }
    __builtin_amdgcn_s_setprio(1);
    #pragma unroll
    for (int mf = 0; mf < 8; mf++)
      #pragma unroll
      for (int nf = 0; nf < 4; nf++)
        acc[mf][nf] = MFMA16(af[mf], bf[nf], acc[mf][nf]);
    __builtin_amdgcn_s_setprio(0);
    if (t <= 28)      asm volatile("s_waitcnt vmcnt(8)\ns_barrier" ::: "memory");
    else if (t == 29) asm volatile("s_waitcnt vmcnt(4)\ns_barrier" ::: "memory");
    else if (t == 30) asm volatile("s_waitcnt vmcnt(0)\ns_barrier" ::: "memory");
  }

  // epilogue: RoPE (q,k) + scatter to (b,h,s,d)
  const int proj = n0 >> 10;   // uniform per block (256 | 1024)
  h16* dst = proj == 0 ? qh : (proj == 1 ? kh : vh);
  #pragma unroll
  for (int mf = 0; mf < 8; mf++) {
    #pragma unroll
    for (int nf = 0; nf < 4; nf++) {
      #pragma unroll
      for (int r = 0; r < 4; r++) {
        float v = acc[mf][nf][r];
        int row = wr*128 + mf*16 + ((l >> 4) << 2) + r;
        int col = wc*64 + nf*16 + (l & 15);
        int tk = m0 + row;
        int b = tk >> 13;
        int s = tk & 8191;
        int e = (n0 & 1023) + col;
        int hh = e >> 6, d = e & 63;
        if (proj < 2) {
          float2 cs = *(const float2*)(fc + ((size_t)s*32 + (d >> 1))*2);
          float p = __shfl_xor(v, 1);
          v = (d & 1) ? (v*cs.x + p*cs.y) : (v*cs.x - p*cs.y);
        }
        dst[((size_t)((b*16 + hh)*8192 + s) << 6) + d] = (h16)v;
      }
    }
  }
}

// ---------------- transpose: K->(K^T * k_dec), V->V^T  (per bh, per chunk) --
__global__ __launch_bounds__(256) void k_tr(
    const h16* __restrict__ kh, const h16* __restrict__ vh,
    h16* __restrict__ kts, h16* __restrict__ vt)
{
  __shared__ __align__(16) h16 tl[128*64];
  __shared__ float dt[128];
  const int tid = threadIdx.x;
  const int st = blockIdx.x;
  const int bh = blockIdx.y;
  const int h = bh & 15;
  if (tid < 128) {
    float slope = exp2f(-0.5f * (float)(h + 1));
    dt[tid] = expf(-slope * (float)(127 - tid));
  }
  const size_t ibase = ((size_t)bh*8192 + st*128) * 64;
  const size_t obase = (size_t)bh*64*8192 + st*128;
  const int cr = tid >> 3, c8 = tid & 7;

  for (int which = 0; which < 2; ++which) {
    const h16* src = which ? vh : kh;
    h16* dstp = which ? vt : kts;
    __syncthreads();
    #pragma unroll
    for (int i = 0; i < 4; i++) {
      int r = i*32 + cr;
      h16x8 v = *(const h16x8*)(src + ibase + (size_t)r*64 + c8*8);
      int slot = (c8 + ((r >> 3) & 7)) & 7;
      *(h16x8*)(tl + r*64 + slot*8) = v;
    }
    __syncthreads();
    #pragma unroll
    for (int i = 0; i < 4; i++) {
      int chunk = i*256 + tid;
      int d = chunk >> 4;
      int j8 = chunk & 15;
      h16x8 o;
      #pragma unroll
      for (int jj = 0; jj < 8; jj++) {
        int c = j8*8 + jj;
        int pos = (d + ((c >> 3) & 7)*8) & 63;
        float fv = (float)tl[c*64 + pos];
        if (!which) fv *= dt[c];
        o[jj] = (h16)fv;
      }
      *(h16x8*)(dstp + obase + (size_t)d*8192 + j8*8) = o;
    }
  }
}

// ---------------- per-chunk KV^T state ------------------------------------
__global__ __launch_bounds__(256) void k_kv(
    const h16* __restrict__ kts, const h16* __restrict__ vt,
    float* __restrict__ T)
{
  const int tid = threadIdx.x;
  const int t = blockIdx.x;
  const int bh = blockIdx.y;
  const int w = tid >> 6, l = tid & 63;
  const h16* vb = vt  + (size_t)bh*64*8192 + t*128;
  const h16* kb = kts + (size_t)bh*64*8192 + t*128;
  f32x4 acc[4] = {};
  h16x8 a[4];
  #pragma unroll
  for (int ks = 0; ks < 4; ks++)
    a[ks] = *(const h16x8*)(vb + (size_t)(w*16 + (l & 15))*8192 + ks*32 + (l >> 4)*8);
  #pragma unroll
  for (int nf = 0; nf < 4; nf++) {
    #pragma unroll
    for (int ks = 0; ks < 4; ks++) {
      h16x8 bfr = *(const h16x8*)(kb + (size_t)(nf*16 + (l & 15))*8192 + ks*32 + (l >> 4)*8);
      acc[nf] = MFMA16(a[ks], bfr, acc[nf]);
    }
  }
  float* Tb = T + ((size_t)bh*64 + t)*4096;
  #pragma unroll
  for (int nf = 0; nf < 4; nf++)
    #pragma unroll
    for (int r = 0; r < 4; r++) {
      int e = w*16 + ((l >> 4) << 2) + r;
      int d = nf*16 + (l & 15);
      Tb[e*64 + d] = acc[nf][r];
    }
}

// ---------------- decay prefix scan over chunks (1 elem/thread) -----------
__global__ __launch_bounds__(256) void k_scan(const float* __restrict__ T,
                                              h16* __restrict__ ph) {
  const int bh = blockIdx.x;                       // 0..31
  const int j  = blockIdx.y * 256 + threadIdx.x;   // 0..4095
  const int h = bh & 15;
  const float cdec = expf(-exp2f(-0.5f*(float)(h+1)) * 128.0f);
  const float* Tb = T + (size_t)bh*64*4096 + j;
  h16* pb = ph + (size_t)bh*64*4096 + j;
  float run = 0.f;
  for (int t = 0; t < 64; t++) {
    float kv = Tb[(size_t)t*4096];
    pb[(size_t)t*4096] = (h16)run;
    run = cdec*run + kv;
  }
}

// ---------------- per-chunk attention output ------------------------------
__global__ __launch_bounds__(256) void k_att(
    const h16* __restrict__ qh, const h16* __restrict__ kh,
    const h16* __restrict__ vt, const h16* __restrict__ ph,
    float* __restrict__ out)
{
  __shared__ __align__(16) h16 P[128*144];
  __shared__ float dt[128], qd[128];
  const int tid = threadIdx.x;
  const int t = blockIdx.x;
  const int bh = blockIdx.y;
  const int b = bh >> 4, h = bh & 15;
  if (tid < 128) {
    float slope = exp2f(-0.5f*(float)(h+1));
    dt[tid] = expf(-slope*(float)tid);
    qd[tid] = expf(-slope*(float)(tid+1));
  }
  __syncthreads();
  const int w = tid >> 6, l = tid & 63;
  const int iw = w * 32;
  const h16* qb = qh + ((size_t)bh*8192 + t*128)*64;
  const h16* kb = kh + ((size_t)bh*8192 + t*128)*64;
  const h16* vb = vt + (size_t)bh*64*8192 + t*128;
  const h16* pb = ph + ((size_t)bh*64 + t)*4096;

  h16x8 aq[2][2];
  #pragma unroll
  for (int mf = 0; mf < 2; mf++)
    #pragma unroll
    for (int ks = 0; ks < 2; ks++)
      aq[mf][ks] = *(const h16x8*)(qb + (size_t)(iw + mf*16 + (l & 15))*64 + ks*32 + (l >> 4)*8);

  f32x4 sc[2][8] = {};
  #pragma unroll
  for (int nf = 0; nf < 8; nf++) {
    #pragma unroll
    for (int ks = 0; ks < 2; ks++) {
      h16x8 bk = *(const h16x8*)(kb + (size_t)(nf*16 + (l & 15))*64 + ks*32 + (l >> 4)*8);
      sc[0][nf] = MFMA16(aq[0][ks], bk, sc[0][nf]);
      sc[1][nf] = MFMA16(aq[1][ks], bk, sc[1][nf]);
    }
  }
  #pragma unroll
  for (int mf = 0; mf < 2; mf++) {
    #pragma unroll
    for (int nf = 0; nf < 8; nf++) {
      #pragma unroll
      for (int r = 0; r < 4; r++) {
        int i = iw + mf*16 + ((l >> 4) << 2) + r;
        int j = nf*16 + (l & 15);
        int diff = i - j;
        float v = diff >= 0 ? sc[mf][nf][r]*dt[diff] : 0.f;
        P[i*144 + j] = (h16)v;
      }
    }
  }
  f32x4 ao[2][4] = {};
  #pragma unroll
  for (int kc = 0; kc < 4; kc++) {
    h16x8 ap0 = *(const h16x8*)(P + (size_t)(iw + (l & 15))*144 + kc*32 + (l >> 4)*8);
    h16x8 ap1 = *(const h16x8*)(P + (size_t)(iw + 16 + (l & 15))*144 + kc*32 + (l >> 4)*8);
    #pragma unroll
    for (int nf = 0; nf < 4; nf++) {
      h16x8 bv = *(const h16x8*)(vb + (size_t)(nf*16 + (l & 15))*8192 + kc*32 + (l >> 4)*8);
      ao[0][nf] = MFMA16(ap0, bv, ao[0][nf]);
      ao[1][nf] = MFMA16(ap1, bv, ao[1][nf]);
    }
  }
  f32x4 a2[2][4] = {};
  #pragma unroll
  for (int ks = 0; ks < 2; ks++) {
    #pragma unroll
    for (int nf = 0; nf < 4; nf++) {
      h16x8 bs = *(const h16x8*)(pb + (size_t)(nf*16 + (l & 15))*64 + ks*32 + (l >> 4)*8);
      a2[0][nf] = MFMA16(aq[0][ks], bs, a2[0][nf]);
      a2[1][nf] = MFMA16(aq[1][ks], bs, a2[1][nf]);
    }
  }
  #pragma unroll
  for (int mf = 0; mf < 2; mf++) {
    #pragma unroll
    for (int nf = 0; nf < 4; nf++) {
      #pragma unroll
      for (int r = 0; r < 4; r++) {
        int i = iw + mf*16 + ((l >> 4) << 2) + r;
        int e = nf*16 + (l & 15);
        float o = ao[mf][nf][r] + qd[i]*a2[mf][nf][r];
        int s = t*128 + i;
        out[((size_t)(b*8192 + s))*1024 + h*64 + e] = o;
      }
    }
  }
}

// ---------------- RMSNorm (per token) -> fp16 -----------------------------
__global__ __launch_bounds__(256) void k_rms(const float* __restrict__ o,
                                             const float* __restrict__ rw,
                                             h16* __restrict__ an) {
  const int tid = threadIdx.x;
  const size_t base = (size_t)blockIdx.x * 1024;
  float4 v = *(const float4*)(o + base + tid*4);
  float ss = v.x*v.x + v.y*v.y + v.z*v.z + v.w*v.w;
  #pragma unroll
  for (int off = 32; off > 0; off >>= 1) ss += __shfl_down(ss, off);
  __shared__ float red[4];
  if ((tid & 63) == 0) red[tid >> 6] = ss;
  __syncthreads();
  float f = rsqrtf((red[0]+red[1]+red[2]+red[3]) * (1.0f/1024.0f) + 1e-5f);
  float4 wv = *(const float4*)(rw + tid*4);
  h16x4 r;
  r[0] = (h16)(v.x*f*wv.x); r[1] = (h16)(v.y*f*wv.y);
  r[2] = (h16)(v.z*f*wv.z); r[3] = (h16)(v.w*f*wv.w);
  *(h16x4*)(an + base + tid*4) = r;
}

// ---------------- final GEMM: out = An @ wo^T (M=16384, N=1024, K=1024) ---
__global__ __launch_bounds__(512, 2) void k_out(
    const h16* __restrict__ an, const h16* __restrict__ woh,
    float* __restrict__ out)
{
  extern __shared__ __align__(16) char smem[];
  h16* lA = (h16*)smem;
  h16* lB = (h16*)(smem + 65536);
  const int tid = threadIdx.x;
  const int w = tid >> 6, l = tid & 63;
  const int orig = blockIdx.y * gridDim.x + blockIdx.x;
  const int cpx = (gridDim.x * gridDim.y) >> 3;
  const int swz = (orig & 7) * cpx + (orig >> 3);
  const int m0 = (swz & 63) << 8;
  const int n0 = (swz >> 6) << 8;
  const int wr = w >> 2, wc = w & 3;
  const h16* At = an + (size_t)m0 * 1024;
  const h16* Bt = woh + (size_t)n0 * 1024;
  const int srow0 = w*16 + (l >> 2);
  const int sl0 = l & 3;

  auto stage = [&](int kt) {
    const int kb = (kt & 3) * 16384;
    #pragma unroll
    for (int c = 0; c < 2; c++) {
      int row = c*128 + srow0;
      int sl = sl0 ^ ((row >> 1) & 3);
      GLOAD16(At + (size_t)row*1024 + kt*32 + sl*8, (char*)lA + kb + c*8192 + w*1024);
      GLOAD16(Bt + (size_t)row*1024 + kt*32 + sl*8, (char*)lB + kb + c*8192 + w*1024);
    }
  };

  f32x4 acc[8][4] = {};
  stage(0); stage(1); stage(2);
  asm volatile("s_waitcnt vmcnt(8)\ns_barrier" ::: "memory");

  for (int t = 0; t < 32; ++t) {
    if (t < 29) stage(t + 3);
    const h16* bufA = lA + (t & 3) * 8192;
    const h16* bufB = lB + (t & 3) * 8192;
    h16x8 af[8], bf[4];
    #pragma unroll
    for (int mf = 0; mf < 8; mf++) {
      int row = wr*128 + mf*16 + (l & 15);
      int sl = (l >> 4) ^ ((row >> 1) & 3);
      af[mf] = *(const h16x8*)(bufA + row*32 + sl*8);
    }
    #pragma unroll
    for (int nf = 0; nf < 4; nf++) {
      int row = wc*64 + nf*16 + (l & 15);
      int sl = (l >> 4) ^ ((row >> 1) & 3);
      bf[nf] = *(const h16x8*)(bufB + row*32 + sl*8);
    }
    __builtin_amdgcn_s_setprio(1);
    #pragma unroll
    for (int mf = 0; mf < 8; mf++)
      #pragma unroll
      for (int nf = 0; nf < 4; nf++)
        acc[mf][nf] = MFMA16(af[mf], bf[nf], acc[mf][nf]);
    __builtin_amdgcn_s_setprio(0);
    if (t <= 28)      asm volatile("s_waitcnt vmcnt(8)\ns_barrier" ::: "memory");
    else if (t == 29) asm volatile("s_waitcnt vmcnt(4)\ns_barrier" ::: "memory");
    else if (t == 30) asm volatile("s_waitcnt vmcnt(0)\ns_barrier" ::: "memory");
  }

  #pragma unroll
  for (int mf = 0; mf < 8; mf++)
    #pragma unroll
    for (int nf = 0; nf < 4; nf++)
      #pragma unroll
      for (int r = 0; r < 4; r++) {
        int row = wr*128 + mf*16 + ((l >> 4) << 2) + r;
        int col = wc*64 + nf*16 + (l & 15);
        out[(size_t)(m0 + row)*1024 + n0 + col] = acc[mf][nf][r];
      }
}

// --------------------------------------------------------------------------
extern "C" void kernel_launch(void* const* d_in, const int* in_sizes, int n_in,
                              void* d_out, int out_size, void* d_ws, size_t ws_size,
                              hipStream_t stream) {
  const float* x  = (const float*)d_in[0];
  const float* fc = (const float*)d_in[1];
  const float* wq = (const float*)d_in[2];
  const float* wk = (const float*)d_in[3];
  const float* wv = (const float*)d_in[4];
  const float* wo = (const float*)d_in[5];
  const float* rw = (const float*)d_in[6];
  float* out = (float*)d_out;

  char* p = (char*)d_ws;
  const size_t SZ = 33554432;
  h16* xh  = (h16*)(p);
  h16* qh  = (h16*)(p + SZ);
  h16* kh  = (h16*)(p + 2*SZ);
  h16* vh  = (h16*)(p + 3*SZ);
  h16* kts = (h16*)(p + 4*SZ);
  h16* vt  = (h16*)(p + 5*SZ);
  float* T = (float*)(p + 6*SZ);
  h16* w3  = (h16*)(p + 7*SZ);
  h16* woh = (h16*)(p + 7*SZ + 6291456);

  (void)hipFuncSetAttribute((const void*)k_qkv, hipFuncAttributeMaxDynamicSharedMemorySize, 131072);
  (void)hipFuncSetAttribute((const void*)k_out, hipFuncAttributeMaxDynamicSharedMemorySize, 131072);

  hipLaunchKernelGGL(k_cvt, dim3(8192), dim3(256), 0, stream, x, xh, 16777216);
  hipLaunchKernelGGL(k_cvt, dim3(512), dim3(256), 0, stream, wq, w3, 1048576);
  hipLaunchKernelGGL(k_cvt, dim3(512), dim3(256), 0, stream, wk, w3 + 1048576, 1048576);
  hipLaunchKernelGGL(k_cvt, dim3(512), dim3(256), 0, stream, wv, w3 + 2097152, 1048576);
  hipLaunchKernelGGL(k_cvt, dim3(512), dim3(256), 0, stream, wo, woh, 1048576);

  hipLaunchKernelGGL(k_qkv, dim3(64, 12), dim3(512), 131072, stream, xh, w3, fc, qh, kh, vh);
  hipLaunchKernelGGL(k_tr,  dim3(64, 32), dim3(256), 0, stream, kh, vh, kts, vt);
  hipLaunchKernelGGL(k_kv,  dim3(64, 32), dim3(256), 0, stream, kts, vt, T);
  h16* ph = vh;
  hipLaunchKernelGGL(k_scan, dim3(32, 16), dim3(256), 0, stream, T, ph);
  hipLaunchKernelGGL(k_att, dim3(64, 32), dim3(256), 0, stream, qh, kh, vt, ph, out);
  h16* an = xh;
  hipLaunchKernelGGL(k_rms, dim3(16384), dim3(256), 0, stream, out, rw, an);
  hipLaunchKernelGGL(k_out, dim3(64, 4), dim3(512), 131072, stream, an, woh, out);
}

// Round 3
// 403.391 us; speedup vs baseline: 1.0246x; 1.0246x over previous
//
#include <hip/hip_runtime.h>

// B=2 S=8192 E=1024 H=16 D=64 CHUNK=128 NC=64

using h16   = _Float16;
using h16x8 = __attribute__((ext_vector_type(8))) _Float16;
using h16x4 = __attribute__((ext_vector_type(4))) _Float16;
using f32x4 = __attribute__((ext_vector_type(4))) float;

#define MFMA16(a,b,c) __builtin_amdgcn_mfma_f32_16x16x32_f16(a,b,c,0,0,0)

#define GLOAD16(gp, lp) __builtin_amdgcn_global_load_lds( \
    (const __attribute__((address_space(1))) void*)(gp),  \
    (__attribute__((address_space(3))) void*)(lp), 16, 0, 0)

// ---------------- fp32 -> fp16 convert (8 elems/thread) ----------------
__global__ __launch_bounds__(256) void k_cvt(const float* __restrict__ s,
                                             h16* __restrict__ d, int n) {
  int i = (blockIdx.x * 256 + threadIdx.x) * 8;
  if (i >= n) return;
  float4 a = *(const float4*)(s + i);
  float4 b = *(const float4*)(s + i + 4);
  h16x8 o;
  o[0]=(h16)a.x; o[1]=(h16)a.y; o[2]=(h16)a.z; o[3]=(h16)a.w;
  o[4]=(h16)b.x; o[5]=(h16)b.y; o[6]=(h16)b.z; o[7]=(h16)b.w;
  *(h16x8*)(d + i) = o;
}

// ===== 256x256 fine-phased GEMM main loop (BK=32, 4-buf ring, counted vmcnt)
// LDS per operand buffer: 256 logical rows x 32 fp16, packed as 128 phys rows
// of 128B (rows 2p,2p+1 interleaved at 16B granule, 3-bit XOR swizzle).
__device__ __forceinline__ void gemm_mainloop(
    const h16* __restrict__ At, const h16* __restrict__ Bt,
    char* lA, char* lB, int w, int l, f32x4 (&acc)[8][4])
{
  const int wr = w >> 2, wc = w & 3;
  // stage mapping (2 loads c=0,1): phys row p -> (logical row, 16B slot)
  int rr[2], ss[2];
  #pragma unroll
  for (int c = 0; c < 2; c++) {
    int p = (c*8 + w)*8 + (l >> 3);          // 0..127
    int idx3 = (l & 7) ^ (p & 7);
    rr[c] = 2*p + (idx3 >> 2);               // 0..255
    ss[c] = idx3 & 3;                        // 8-fp16 slot in 32-col row
  }
  // fragment-read per-thread constant offsets
  const int phys16 = (((l & 1) << 2) | (l >> 4)) ^ ((l >> 1) & 7);
  const int aoff = (wr*64 + ((l & 15) >> 1))*128 + phys16*16;
  const int boff = (wc*32 + ((l & 15) >> 1))*128 + phys16*16;

  auto stageA = [&](int u) {
    char* dst = lA + (u & 3)*16384;
    #pragma unroll
    for (int c = 0; c < 2; c++)
      GLOAD16(At + (size_t)rr[c]*1024 + u*32 + ss[c]*8, dst + (c*8 + w)*1024);
  };
  auto stageB = [&](int u) {
    char* dst = lB + (u & 3)*16384;
    #pragma unroll
    for (int c = 0; c < 2; c++)
      GLOAD16(Bt + (size_t)rr[c]*1024 + u*32 + ss[c]*8, dst + (c*8 + w)*1024);
  };

  // prologue: A0,B0 drained by the vmcnt(10); A1,B1,A2,B2,B3 stay in flight
  stageA(0); stageB(0); stageA(1); stageB(1); stageA(2); stageB(2); stageB(3);
  asm volatile("s_waitcnt vmcnt(10)\ns_barrier" ::: "memory");

  for (int kt = 0; kt < 32; ++kt) {
    const char* bufA = lA + (kt & 3)*16384;
    const char* bufB = lB + (kt & 3)*16384;
    h16x8 af[4], bf[4];
    // ---- phase q0: mf 0-3, read B (ks covers full BK=32) ----
    #pragma unroll
    for (int mf = 0; mf < 4; mf++)
      af[mf] = *(const h16x8*)(bufA + aoff + mf*1024);
    #pragma unroll
    for (int nf = 0; nf < 4; nf++)
      bf[nf] = *(const h16x8*)(bufB + boff + nf*1024);
    if (kt < 29) stageA(kt + 3);   // target buf (kt+3)&3 != kt&3: safe
    __builtin_amdgcn_s_setprio(1);
    #pragma unroll
    for (int mf = 0; mf < 4; mf++)
      #pragma unroll
      for (int nf = 0; nf < 4; nf++)
        acc[mf][nf] = MFMA16(af[mf], bf[nf], acc[mf][nf]);
    __builtin_amdgcn_s_setprio(0);
    asm volatile("s_waitcnt vmcnt(10)\ns_barrier" ::: "memory");
    // ---- phase q1: mf 4-7, reuse B regs ----
    #pragma unroll
    for (int mf = 0; mf < 4; mf++)
      af[mf] = *(const h16x8*)(bufA + aoff + 4096 + mf*1024);
    if (kt < 28) stageB(kt + 4);   // B(kt) region fully read at q0 (barrier'd)
    __builtin_amdgcn_s_setprio(1);
    #pragma unroll
    for (int mf = 0; mf < 4; mf++)
      #pragma unroll
      for (int nf = 0; nf < 4; nf++)
        acc[4+mf][nf] = MFMA16(af[mf], bf[nf], acc[4+mf][nf]);
    __builtin_amdgcn_s_setprio(0);
    // graduated tail drain: kt29 needs A29,B29; kt30 A30,B30; kt31 A31,B31
    if (kt < 28)      asm volatile("s_waitcnt vmcnt(10)\ns_barrier" ::: "memory");
    else if (kt == 28) asm volatile("s_waitcnt vmcnt(8)\ns_barrier" ::: "memory");
    else if (kt == 29) asm volatile("s_waitcnt vmcnt(4)\ns_barrier" ::: "memory");
    else               asm volatile("s_waitcnt vmcnt(0)\ns_barrier" ::: "memory");
  }
}

// ---------------- QKV GEMM (M=16384, N=3072, K=1024) + RoPE ----------------
__global__ __launch_bounds__(512, 2) void k_qkv(
    const h16* __restrict__ xh, const h16* __restrict__ w3,
    const float* __restrict__ fc,
    h16* __restrict__ qh, h16* __restrict__ kh, h16* __restrict__ vh)
{
  extern __shared__ __align__(16) char smem[];   // 128 KiB
  char* lA = smem;
  char* lB = smem + 65536;
  const int tid = threadIdx.x;
  const int w = tid >> 6, l = tid & 63;
  const int orig = blockIdx.y * gridDim.x + blockIdx.x;
  const int cpx = (gridDim.x * gridDim.y) >> 3;
  const int swz = (orig & 7) * cpx + (orig >> 3);
  const int m0 = (swz & 63) << 8;
  const int n0 = (swz >> 6) << 8;
  const int wr = w >> 2, wc = w & 3;

  f32x4 acc[8][4] = {};
  gemm_mainloop(xh + (size_t)m0 * 1024, w3 + (size_t)n0 * 1024, lA, lB, w, l, acc);

  // epilogue: RoPE (q,k) + scatter to (b,h,s,d)
  const int proj = n0 >> 10;   // 0=q 1=k 2=v (uniform per block)
  h16* dst = proj == 0 ? qh : (proj == 1 ? kh : vh);
  #pragma unroll
  for (int mf = 0; mf < 8; mf++) {
    #pragma unroll
    for (int nf = 0; nf < 4; nf++) {
      #pragma unroll
      for (int r = 0; r < 4; r++) {
        float v = acc[mf][nf][r];
        int row = wr*128 + mf*16 + ((l >> 4) << 2) + r;
        int col = wc*64 + nf*16 + (l & 15);
        int tk = m0 + row;
        int b = tk >> 13;
        int s = tk & 8191;
        int e = (n0 & 1023) + col;
        int hh = e >> 6, d = e & 63;
        if (proj < 2) {
          float2 cs = *(const float2*)(fc + ((size_t)s*32 + (d >> 1))*2);
          float p = __shfl_xor(v, 1);
          v = (d & 1) ? (v*cs.x + p*cs.y) : (v*cs.x - p*cs.y);
        }
        dst[((size_t)((b*16 + hh)*8192 + s) << 6) + d] = (h16)v;
      }
    }
  }
}

// ---------------- final GEMM: out = An @ wo^T (M=16384, N=1024, K=1024) ---
__global__ __launch_bounds__(512, 2) void k_out(
    const h16* __restrict__ an, const h16* __restrict__ woh,
    float* __restrict__ out)
{
  extern __shared__ __align__(16) char smem[];
  char* lA = smem;
  char* lB = smem + 65536;
  const int tid = threadIdx.x;
  const int w = tid >> 6, l = tid & 63;
  const int orig = blockIdx.y * gridDim.x + blockIdx.x;
  const int cpx = (gridDim.x * gridDim.y) >> 3;
  const int swz = (orig & 7) * cpx + (orig >> 3);
  const int m0 = (swz & 63) << 8;
  const int n0 = (swz >> 6) << 8;
  const int wr = w >> 2, wc = w & 3;

  f32x4 acc[8][4] = {};
  gemm_mainloop(an + (size_t)m0 * 1024, woh + (size_t)n0 * 1024, lA, lB, w, l, acc);

  #pragma unroll
  for (int mf = 0; mf < 8; mf++)
    #pragma unroll
    for (int nf = 0; nf < 4; nf++)
      #pragma unroll
      for (int r = 0; r < 4; r++) {
        int row = wr*128 + mf*16 + ((l >> 4) << 2) + r;
        int col = wc*64 + nf*16 + (l & 15);
        out[(size_t)(m0 + row)*1024 + n0 + col] = acc[mf][nf][r];
      }
}

// ---------------- transpose: K->(K^T * k_dec), V->V^T  (per bh, per chunk) --
__global__ __launch_bounds__(256) void k_tr(
    const h16* __restrict__ kh, const h16* __restrict__ vh,
    h16* __restrict__ kts, h16* __restrict__ vt)
{
  __shared__ __align__(16) h16 tl[128*64];
  __shared__ float dt[128];
  const int tid = threadIdx.x;
  const int st = blockIdx.x;
  const int bh = blockIdx.y;
  const int h = bh & 15;
  if (tid < 128) {
    float slope = exp2f(-0.5f * (float)(h + 1));
    dt[tid] = expf(-slope * (float)(127 - tid));
  }
  const size_t ibase = ((size_t)bh*8192 + st*128) * 64;
  const size_t obase = (size_t)bh*64*8192 + st*128;
  const int cr = tid >> 3, c8 = tid & 7;

  for (int which = 0; which < 2; ++which) {
    const h16* src = which ? vh : kh;
    h16* dstp = which ? vt : kts;
    __syncthreads();
    #pragma unroll
    for (int i = 0; i < 4; i++) {
      int r = i*32 + cr;
      h16x8 v = *(const h16x8*)(src + ibase + (size_t)r*64 + c8*8);
      int slot = (c8 + ((r >> 3) & 7)) & 7;
      *(h16x8*)(tl + r*64 + slot*8) = v;
    }
    __syncthreads();
    #pragma unroll
    for (int i = 0; i < 4; i++) {
      int chunk = i*256 + tid;
      int d = chunk >> 4;
      int j8 = chunk & 15;
      h16x8 o;
      #pragma unroll
      for (int jj = 0; jj < 8; jj++) {
        int c = j8*8 + jj;
        int pos = (d + ((c >> 3) & 7)*8) & 63;
        float fv = (float)tl[c*64 + pos];
        if (!which) fv *= dt[c];
        o[jj] = (h16)fv;
      }
      *(h16x8*)(dstp + obase + (size_t)d*8192 + j8*8) = o;
    }
  }
}

// ---------------- per-chunk KV^T state ------------------------------------
__global__ __launch_bounds__(256) void k_kv(
    const h16* __restrict__ kts, const h16* __restrict__ vt,
    float* __restrict__ T)
{
  const int tid = threadIdx.x;
  const int t = blockIdx.x;
  const int bh = blockIdx.y;
  const int w = tid >> 6, l = tid & 63;
  const h16* vb = vt  + (size_t)bh*64*8192 + t*128;
  const h16* kb = kts + (size_t)bh*64*8192 + t*128;
  f32x4 acc[4] = {};
  h16x8 a[4];
  #pragma unroll
  for (int ks = 0; ks < 4; ks++)
    a[ks] = *(const h16x8*)(vb + (size_t)(w*16 + (l & 15))*8192 + ks*32 + (l >> 4)*8);
  #pragma unroll
  for (int nf = 0; nf < 4; nf++) {
    #pragma unroll
    for (int ks = 0; ks < 4; ks++) {
      h16x8 bfr = *(const h16x8*)(kb + (size_t)(nf*16 + (l & 15))*8192 + ks*32 + (l >> 4)*8);
      acc[nf] = MFMA16(a[ks], bfr, acc[nf]);
    }
  }
  float* Tb = T + ((size_t)bh*64 + t)*4096;
  #pragma unroll
  for (int nf = 0; nf < 4; nf++)
    #pragma unroll
    for (int r = 0; r < 4; r++) {
      int e = w*16 + ((l >> 4) << 2) + r;
      int d = nf*16 + (l & 15);
      Tb[e*64 + d] = acc[nf][r];
    }
}

// ---------------- decay prefix scan over chunks (1 elem/thread) -----------
__global__ __launch_bounds__(256) void k_scan(const float* __restrict__ T,
                                              h16* __restrict__ ph) {
  const int bh = blockIdx.x;
  const int j  = blockIdx.y * 256 + threadIdx.x;
  const int h = bh & 15;
  const float cdec = expf(-exp2f(-0.5f*(float)(h+1)) * 128.0f);
  const float* Tb = T + (size_t)bh*64*4096 + j;
  h16* pb = ph + (size_t)bh*64*4096 + j;
  float run = 0.f;
  for (int t = 0; t < 64; t++) {
    float kv = Tb[(size_t)t*4096];
    pb[(size_t)t*4096] = (h16)run;
    run = cdec*run + kv;
  }
}

// ---------------- per-chunk attention output ------------------------------
__global__ __launch_bounds__(256) void k_att(
    const h16* __restrict__ qh, const h16* __restrict__ kh,
    const h16* __restrict__ vt, const h16* __restrict__ ph,
    float* __restrict__ out)
{
  __shared__ __align__(16) h16 P[128*144];
  __shared__ float dt[128], qd[128];
  const int tid = threadIdx.x;
  const int t = blockIdx.x;
  const int bh = blockIdx.y;
  const int b = bh >> 4, h = bh & 15;
  if (tid < 128) {
    float slope = exp2f(-0.5f*(float)(h+1));
    dt[tid] = expf(-slope*(float)tid);
    qd[tid] = expf(-slope*(float)(tid+1));
  }
  __syncthreads();
  const int w = tid >> 6, l = tid & 63;
  const int iw = w * 32;
  const h16* qb = qh + ((size_t)bh*8192 + t*128)*64;
  const h16* kb = kh + ((size_t)bh*8192 + t*128)*64;
  const h16* vb = vt + (size_t)bh*64*8192 + t*128;
  const h16* pb = ph + ((size_t)bh*64 + t)*4096;

  h16x8 aq[2][2];
  #pragma unroll
  for (int mf = 0; mf < 2; mf++)
    #pragma unroll
    for (int ks = 0; ks < 2; ks++)
      aq[mf][ks] = *(const h16x8*)(qb + (size_t)(iw + mf*16 + (l & 15))*64 + ks*32 + (l >> 4)*8);

  f32x4 sc[2][8] = {};
  #pragma unroll
  for (int nf = 0; nf < 8; nf++) {
    #pragma unroll
    for (int ks = 0; ks < 2; ks++) {
      h16x8 bk = *(const h16x8*)(kb + (size_t)(nf*16 + (l & 15))*64 + ks*32 + (l >> 4)*8);
      sc[0][nf] = MFMA16(aq[0][ks], bk, sc[0][nf]);
      sc[1][nf] = MFMA16(aq[1][ks], bk, sc[1][nf]);
    }
  }
  #pragma unroll
  for (int mf = 0; mf < 2; mf++) {
    #pragma unroll
    for (int nf = 0; nf < 8; nf++) {
      #pragma unroll
      for (int r = 0; r < 4; r++) {
        int i = iw + mf*16 + ((l >> 4) << 2) + r;
        int j = nf*16 + (l & 15);
        int diff = i - j;
        float v = diff >= 0 ? sc[mf][nf][r]*dt[diff] : 0.f;
        P[i*144 + j] = (h16)v;
      }
    }
  }
  f32x4 ao[2][4] = {};
  #pragma unroll
  for (int kc = 0; kc < 4; kc++) {
    h16x8 ap0 = *(const h16x8*)(P + (size_t)(iw + (l & 15))*144 + kc*32 + (l >> 4)*8);
    h16x8 ap1 = *(const h16x8*)(P + (size_t)(iw + 16 + (l & 15))*144 + kc*32 + (l >> 4)*8);
    #pragma unroll
    for (int nf = 0; nf < 4; nf++) {
      h16x8 bv = *(const h16x8*)(vb + (size_t)(nf*16 + (l & 15))*8192 + kc*32 + (l >> 4)*8);
      ao[0][nf] = MFMA16(ap0, bv, ao[0][nf]);
      ao[1][nf] = MFMA16(ap1, bv, ao[1][nf]);
    }
  }
  f32x4 a2[2][4] = {};
  #pragma unroll
  for (int ks = 0; ks < 2; ks++) {
    #pragma unroll
    for (int nf = 0; nf < 4; nf++) {
      h16x8 bs = *(const h16x8*)(pb + (size_t)(nf*16 + (l & 15))*64 + ks*32 + (l >> 4)*8);
      a2[0][nf] = MFMA16(aq[0][ks], bs, a2[0][nf]);
      a2[1][nf] = MFMA16(aq[1][ks], bs, a2[1][nf]);
    }
  }
  #pragma unroll
  for (int mf = 0; mf < 2; mf++) {
    #pragma unroll
    for (int nf = 0; nf < 4; nf++) {
      #pragma unroll
      for (int r = 0; r < 4; r++) {
        int i = iw + mf*16 + ((l >> 4) << 2) + r;
        int e = nf*16 + (l & 15);
        float o = ao[mf][nf][r] + qd[i]*a2[mf][nf][r];
        int s = t*128 + i;
        out[((size_t)(b*8192 + s))*1024 + h*64 + e] = o;
      }
    }
  }
}

// ---------------- RMSNorm (per token) -> fp16 -----------------------------
__global__ __launch_bounds__(256) void k_rms(const float* __restrict__ o,
                                             const float* __restrict__ rw,
                                             h16* __restrict__ an) {
  const int tid = threadIdx.x;
  const size_t base = (size_t)blockIdx.x * 1024;
  float4 v = *(const float4*)(o + base + tid*4);
  float ss = v.x*v.x + v.y*v.y + v.z*v.z + v.w*v.w;
  #pragma unroll
  for (int off = 32; off > 0; off >>= 1) ss += __shfl_down(ss, off);
  __shared__ float red[4];
  if ((tid & 63) == 0) red[tid >> 6] = ss;
  __syncthreads();
  float f = rsqrtf((red[0]+red[1]+red[2]+red[3]) * (1.0f/1024.0f) + 1e-5f);
  float4 wv = *(const float4*)(rw + tid*4);
  h16x4 r;
  r[0] = (h16)(v.x*f*wv.x); r[1] = (h16)(v.y*f*wv.y);
  r[2] = (h16)(v.z*f*wv.z); r[3] = (h16)(v.w*f*wv.w);
  *(h16x4*)(an + base + tid*4) = r;
}

// --------------------------------------------------------------------------
extern "C" void kernel_launch(void* const* d_in, const int* in_sizes, int n_in,
                              void* d_out, int out_size, void* d_ws, size_t ws_size,
                              hipStream_t stream) {
  const float* x  = (const float*)d_in[0];
  const float* fc = (const float*)d_in[1];
  const float* wq = (const float*)d_in[2];
  const float* wk = (const float*)d_in[3];
  const float* wv = (const float*)d_in[4];
  const float* wo = (const float*)d_in[5];
  const float* rw = (const float*)d_in[6];
  float* out = (float*)d_out;

  char* p = (char*)d_ws;
  const size_t SZ = 33554432;
  h16* xh  = (h16*)(p);
  h16* qh  = (h16*)(p + SZ);
  h16* kh  = (h16*)(p + 2*SZ);
  h16* vh  = (h16*)(p + 3*SZ);
  h16* kts = (h16*)(p + 4*SZ);
  h16* vt  = (h16*)(p + 5*SZ);
  float* T = (float*)(p + 6*SZ);
  h16* w3  = (h16*)(p + 7*SZ);
  h16* woh = (h16*)(p + 7*SZ + 6291456);

  (void)hipFuncSetAttribute((const void*)k_qkv, hipFuncAttributeMaxDynamicSharedMemorySize, 131072);
  (void)hipFuncSetAttribute((const void*)k_out, hipFuncAttributeMaxDynamicSharedMemorySize, 131072);

  hipLaunchKernelGGL(k_cvt, dim3(8192), dim3(256), 0, stream, x, xh, 16777216);
  hipLaunchKernelGGL(k_cvt, dim3(512), dim3(256), 0, stream, wq, w3, 1048576);
  hipLaunchKernelGGL(k_cvt, dim3(512), dim3(256), 0, stream, wk, w3 + 1048576, 1048576);
  hipLaunchKernelGGL(k_cvt, dim3(512), dim3(256), 0, stream, wv, w3 + 2097152, 1048576);
  hipLaunchKernelGGL(k_cvt, dim3(512), dim3(256), 0, stream, wo, woh, 1048576);

  hipLaunchKernelGGL(k_qkv, dim3(64, 12), dim3(512), 131072, stream, xh, w3, fc, qh, kh, vh);
  hipLaunchKernelGGL(k_tr,  dim3(64, 32), dim3(256), 0, stream, kh, vh, kts, vt);
  hipLaunchKernelGGL(k_kv,  dim3(64, 32), dim3(256), 0, stream, kts, vt, T);
  h16* ph = vh;
  hipLaunchKernelGGL(k_scan, dim3(32, 16), dim3(256), 0, stream, T, ph);
  hipLaunchKernelGGL(k_att, dim3(64, 32), dim3(256), 0, stream, qh, kh, vt, ph, out);
  h16* an = xh;
  hipLaunchKernelGGL(k_rms, dim3(16384), dim3(256), 0, stream, out, rw, an);
  hipLaunchKernelGGL(k_out, dim3(64, 4), dim3(512), 131072, stream, an, woh, out);
}

// Round 4
// 380.836 us; speedup vs baseline: 1.0853x; 1.0592x over previous
//
#include <hip/hip_runtime.h>

// B=2 S=8192 E=1024 H=16 D=64 CHUNK=128 NC=64

using h16   = _Float16;
using h16x8 = __attribute__((ext_vector_type(8))) _Float16;
using h16x4 = __attribute__((ext_vector_type(4))) _Float16;
using f32x4 = __attribute__((ext_vector_type(4))) float;

#define MFMA16(a,b,c) __builtin_amdgcn_mfma_f32_16x16x32_f16(a,b,c,0,0,0)

#define GLOAD16(gp, lp) __builtin_amdgcn_global_load_lds( \
    (const __attribute__((address_space(1))) void*)(gp),  \
    (__attribute__((address_space(3))) void*)(lp), 16, 0, 0)

// ---------------- fp32 -> fp16 convert (8 elems/thread) ----------------
__global__ __launch_bounds__(256) void k_cvt(const float* __restrict__ s,
                                             h16* __restrict__ d, int n) {
  int i = (blockIdx.x * 256 + threadIdx.x) * 8;
  if (i >= n) return;
  float4 a = *(const float4*)(s + i);
  float4 b = *(const float4*)(s + i + 4);
  h16x8 o;
  o[0]=(h16)a.x; o[1]=(h16)a.y; o[2]=(h16)a.z; o[3]=(h16)a.w;
  o[4]=(h16)b.x; o[5]=(h16)b.y; o[6]=(h16)b.z; o[7]=(h16)b.w;
  *(h16x8*)(d + i) = o;
}

// ===== m97-style 128x128 GEMM mainloop: BK=32, double-buffered LDS via
// global_load_lds (pre-swizzled source), one __syncthreads per K-step.
// LDS tile layout: logical [128 rows][4 slots of 8 fp16]; phys granule
// (16B) at p*128 + g*16 with p=r>>1, g=((r&1)*4+s)^(p&7)  (conflict-free,
// same family as the r1-measured-zero-conflict pattern).
__device__ __forceinline__ void gemm128_loop(
    const h16* __restrict__ At, const h16* __restrict__ Bt,
    h16* lA, h16* lB, int w, int l, int nkt, f32x4 (&acc)[4][4])
{
  // staging: instr c stages phys granule G=(c*4+w)*64+l
  int rr[2], ss[2];
  #pragma unroll
  for (int c = 0; c < 2; c++) {
    int p = (c*4 + w)*8 + (l >> 3);
    int idx = (l & 7) ^ (p & 7);
    rr[c] = 2*p + (idx >> 2);          // logical row 0..127
    ss[c] = idx & 3;                   // 8-fp16 slot
  }
  const int wr = w >> 1, wc = w & 1;
  const int half = (l & 15) >> 1;
  const int gran = (((l & 1) << 2) | (l >> 4)) ^ half;
  const int aoff = wr*4096 + half*128 + gran*16;   // bytes, + mf*1024
  const int boff = wc*4096 + half*128 + gran*16;   // bytes, + nf*1024

  auto stage = [&](int kt) {
    char* dA = (char*)lA + (kt & 1)*8192;
    char* dB = (char*)lB + (kt & 1)*8192;
    #pragma unroll
    for (int c = 0; c < 2; c++) {
      size_t go = (size_t)rr[c]*1024 + kt*32 + ss[c]*8;
      GLOAD16(At + go, dA + (c*4 + w)*1024);
      GLOAD16(Bt + go, dB + (c*4 + w)*1024);
    }
  };

  stage(0);
  __syncthreads();
  for (int kt = 0; kt < nkt; ++kt) {
    if (kt + 1 < nkt) stage(kt + 1);
    const char* bA = (const char*)lA + (kt & 1)*8192;
    const char* bB = (const char*)lB + (kt & 1)*8192;
    h16x8 af[4], bf[4];
    #pragma unroll
    for (int mf = 0; mf < 4; mf++) af[mf] = *(const h16x8*)(bA + aoff + mf*1024);
    #pragma unroll
    for (int nf = 0; nf < 4; nf++) bf[nf] = *(const h16x8*)(bB + boff + nf*1024);
    #pragma unroll
    for (int mf = 0; mf < 4; mf++)
      #pragma unroll
      for (int nf = 0; nf < 4; nf++)
        acc[mf][nf] = MFMA16(af[mf], bf[nf], acc[mf][nf]);
    __syncthreads();
  }
}

// ---------------- QKV GEMM (M=16384, N=3072, K=1024) + RoPE ----------------
__global__ __launch_bounds__(256) void k_qkv(
    const h16* __restrict__ xh, const h16* __restrict__ w3,
    const float* __restrict__ fc,
    h16* __restrict__ qh, h16* __restrict__ kh, h16* __restrict__ vh)
{
  __shared__ __align__(16) h16 lA[2*4096];
  __shared__ __align__(16) h16 lB[2*4096];
  const int tid = threadIdx.x;
  const int w = tid >> 6, l = tid & 63;
  const int m0 = blockIdx.x * 128;
  const int nt = blockIdx.y;
  const int n0 = nt * 128;
  const int wr = w >> 1, wc = w & 1;

  f32x4 acc[4][4] = {};
  gemm128_loop(xh + (size_t)m0*1024, w3 + (size_t)n0*1024, lA, lB, w, l, 32, acc);

  // epilogue: RoPE (q,k) + scatter to (b,h,s,d)
  const int proj = nt >> 3;   // 0=q 1=k 2=v (uniform per block)
  h16* dst = proj == 0 ? qh : (proj == 1 ? kh : vh);
  #pragma unroll
  for (int mf = 0; mf < 4; mf++) {
    #pragma unroll
    for (int nf = 0; nf < 4; nf++) {
      #pragma unroll
      for (int r = 0; r < 4; r++) {
        float v = acc[mf][nf][r];
        int row = wr*64 + mf*16 + ((l >> 4) << 2) + r;
        int col = wc*64 + nf*16 + (l & 15);
        int tk = m0 + row;
        int b = tk >> 13;
        int s = tk & 8191;
        int e = (n0 & 1023) + col;
        int hh = e >> 6, d = e & 63;
        if (proj < 2) {
          float2 cs = *(const float2*)(fc + ((size_t)s*32 + (d >> 1))*2);
          float p = __shfl_xor(v, 1);
          v = (d & 1) ? (v*cs.x + p*cs.y) : (v*cs.x - p*cs.y);
        }
        dst[((size_t)((b*16 + hh)*8192 + s) << 6) + d] = (h16)v;
      }
    }
  }
}

// ---------------- final GEMM: out = An @ wo^T (M=16384, N=1024, K=1024) ---
__global__ __launch_bounds__(256) void k_out(
    const h16* __restrict__ an, const h16* __restrict__ woh,
    float* __restrict__ out)
{
  __shared__ __align__(16) h16 lA[2*4096];
  __shared__ __align__(16) h16 lB[2*4096];
  const int tid = threadIdx.x;
  const int w = tid >> 6, l = tid & 63;
  const int m0 = blockIdx.x * 128;
  const int n0 = blockIdx.y * 128;
  const int wr = w >> 1, wc = w & 1;

  f32x4 acc[4][4] = {};
  gemm128_loop(an + (size_t)m0*1024, woh + (size_t)n0*1024, lA, lB, w, l, 32, acc);

  #pragma unroll
  for (int mf = 0; mf < 4; mf++)
    #pragma unroll
    for (int nf = 0; nf < 4; nf++)
      #pragma unroll
      for (int r = 0; r < 4; r++) {
        int row = wr*64 + mf*16 + ((l >> 4) << 2) + r;
        int col = wc*64 + nf*16 + (l & 15);
        out[(size_t)(m0 + row)*1024 + n0 + col] = acc[mf][nf][r];
      }
}

// ---------------- transpose: K->(K^T * k_dec), V->V^T  (per bh, per chunk) --
__global__ __launch_bounds__(256) void k_tr(
    const h16* __restrict__ kh, const h16* __restrict__ vh,
    h16* __restrict__ kts, h16* __restrict__ vt)
{
  __shared__ __align__(16) h16 tl[128*64];
  __shared__ float dt[128];
  const int tid = threadIdx.x;
  const int st = blockIdx.x;
  const int bh = blockIdx.y;
  const int h = bh & 15;
  if (tid < 128) {
    float slope = exp2f(-0.5f * (float)(h + 1));
    dt[tid] = expf(-slope * (float)(127 - tid));
  }
  const size_t ibase = ((size_t)bh*8192 + st*128) * 64;
  const size_t obase = (size_t)bh*64*8192 + st*128;
  const int cr = tid >> 3, c8 = tid & 7;

  for (int which = 0; which < 2; ++which) {
    const h16* src = which ? vh : kh;
    h16* dstp = which ? vt : kts;
    __syncthreads();
    #pragma unroll
    for (int i = 0; i < 4; i++) {
      int r = i*32 + cr;
      h16x8 v = *(const h16x8*)(src + ibase + (size_t)r*64 + c8*8);
      int slot = (c8 + ((r >> 3) & 7)) & 7;
      *(h16x8*)(tl + r*64 + slot*8) = v;
    }
    __syncthreads();
    #pragma unroll
    for (int i = 0; i < 4; i++) {
      int chunk = i*256 + tid;
      int d = chunk >> 4;
      int j8 = chunk & 15;
      h16x8 o;
      #pragma unroll
      for (int jj = 0; jj < 8; jj++) {
        int c = j8*8 + jj;
        int pos = (d + ((c >> 3) & 7)*8) & 63;
        float fv = (float)tl[c*64 + pos];
        if (!which) fv *= dt[c];
        o[jj] = (h16)fv;
      }
      *(h16x8*)(dstp + obase + (size_t)d*8192 + j8*8) = o;
    }
  }
}

// ---------------- per-chunk KV^T state ------------------------------------
__global__ __launch_bounds__(256) void k_kv(
    const h16* __restrict__ kts, const h16* __restrict__ vt,
    float* __restrict__ T)
{
  const int tid = threadIdx.x;
  const int t = blockIdx.x;
  const int bh = blockIdx.y;
  const int w = tid >> 6, l = tid & 63;
  const h16* vb = vt  + (size_t)bh*64*8192 + t*128;
  const h16* kb = kts + (size_t)bh*64*8192 + t*128;
  f32x4 acc[4] = {};
  h16x8 a[4];
  #pragma unroll
  for (int ks = 0; ks < 4; ks++)
    a[ks] = *(const h16x8*)(vb + (size_t)(w*16 + (l & 15))*8192 + ks*32 + (l >> 4)*8);
  #pragma unroll
  for (int nf = 0; nf < 4; nf++) {
    #pragma unroll
    for (int ks = 0; ks < 4; ks++) {
      h16x8 bfr = *(const h16x8*)(kb + (size_t)(nf*16 + (l & 15))*8192 + ks*32 + (l >> 4)*8);
      acc[nf] = MFMA16(a[ks], bfr, acc[nf]);
    }
  }
  float* Tb = T + ((size_t)bh*64 + t)*4096;
  #pragma unroll
  for (int nf = 0; nf < 4; nf++)
    #pragma unroll
    for (int r = 0; r < 4; r++) {
      int e = w*16 + ((l >> 4) << 2) + r;
      int d = nf*16 + (l & 15);
      Tb[e*64 + d] = acc[nf][r];
    }
}

// ---------------- decay prefix scan over chunks (1 elem/thread) -----------
__global__ __launch_bounds__(256) void k_scan(const float* __restrict__ T,
                                              h16* __restrict__ ph) {
  const int bh = blockIdx.x;
  const int j  = blockIdx.y * 256 + threadIdx.x;
  const int h = bh & 15;
  const float cdec = expf(-exp2f(-0.5f*(float)(h+1)) * 128.0f);
  const float* Tb = T + (size_t)bh*64*4096 + j;
  h16* pb = ph + (size_t)bh*64*4096 + j;
  float run = 0.f;
  for (int t = 0; t < 64; t++) {
    float kv = Tb[(size_t)t*4096];
    pb[(size_t)t*4096] = (h16)run;
    run = cdec*run + kv;
  }
}

// ---------------- per-chunk attention output (O -> fp16) ------------------
__global__ __launch_bounds__(256) void k_att(
    const h16* __restrict__ qh, const h16* __restrict__ kh,
    const h16* __restrict__ vt, const h16* __restrict__ ph,
    h16* __restrict__ oh)
{
  __shared__ __align__(16) h16 P[128*144];
  __shared__ float dt[128], qd[128];
  const int tid = threadIdx.x;
  const int t = blockIdx.x;
  const int bh = blockIdx.y;
  const int b = bh >> 4, h = bh & 15;
  if (tid < 128) {
    float slope = exp2f(-0.5f*(float)(h+1));
    dt[tid] = expf(-slope*(float)tid);
    qd[tid] = expf(-slope*(float)(tid+1));
  }
  __syncthreads();
  const int w = tid >> 6, l = tid & 63;
  const int iw = w * 32;
  const h16* qb = qh + ((size_t)bh*8192 + t*128)*64;
  const h16* kb = kh + ((size_t)bh*8192 + t*128)*64;
  const h16* vb = vt + (size_t)bh*64*8192 + t*128;
  const h16* pb = ph + ((size_t)bh*64 + t)*4096;

  h16x8 aq[2][2];
  #pragma unroll
  for (int mf = 0; mf < 2; mf++)
    #pragma unroll
    for (int ks = 0; ks < 2; ks++)
      aq[mf][ks] = *(const h16x8*)(qb + (size_t)(iw + mf*16 + (l & 15))*64 + ks*32 + (l >> 4)*8);

  f32x4 sc[2][8] = {};
  #pragma unroll
  for (int nf = 0; nf < 8; nf++) {
    #pragma unroll
    for (int ks = 0; ks < 2; ks++) {
      h16x8 bk = *(const h16x8*)(kb + (size_t)(nf*16 + (l & 15))*64 + ks*32 + (l >> 4)*8);
      sc[0][nf] = MFMA16(aq[0][ks], bk, sc[0][nf]);
      sc[1][nf] = MFMA16(aq[1][ks], bk, sc[1][nf]);
    }
  }
  #pragma unroll
  for (int mf = 0; mf < 2; mf++) {
    #pragma unroll
    for (int nf = 0; nf < 8; nf++) {
      #pragma unroll
      for (int r = 0; r < 4; r++) {
        int i = iw + mf*16 + ((l >> 4) << 2) + r;
        int j = nf*16 + (l & 15);
        int diff = i - j;
        float v = diff >= 0 ? sc[mf][nf][r]*dt[diff] : 0.f;
        P[i*144 + j] = (h16)v;
      }
    }
  }
  f32x4 ao[2][4] = {};
  #pragma unroll
  for (int kc = 0; kc < 4; kc++) {
    h16x8 ap0 = *(const h16x8*)(P + (size_t)(iw + (l & 15))*144 + kc*32 + (l >> 4)*8);
    h16x8 ap1 = *(const h16x8*)(P + (size_t)(iw + 16 + (l & 15))*144 + kc*32 + (l >> 4)*8);
    #pragma unroll
    for (int nf = 0; nf < 4; nf++) {
      h16x8 bv = *(const h16x8*)(vb + (size_t)(nf*16 + (l & 15))*8192 + kc*32 + (l >> 4)*8);
      ao[0][nf] = MFMA16(ap0, bv, ao[0][nf]);
      ao[1][nf] = MFMA16(ap1, bv, ao[1][nf]);
    }
  }
  f32x4 a2[2][4] = {};
  #pragma unroll
  for (int ks = 0; ks < 2; ks++) {
    #pragma unroll
    for (int nf = 0; nf < 4; nf++) {
      h16x8 bs = *(const h16x8*)(pb + (size_t)(nf*16 + (l & 15))*64 + ks*32 + (l >> 4)*8);
      a2[0][nf] = MFMA16(aq[0][ks], bs, a2[0][nf]);
      a2[1][nf] = MFMA16(aq[1][ks], bs, a2[1][nf]);
    }
  }
  #pragma unroll
  for (int mf = 0; mf < 2; mf++) {
    #pragma unroll
    for (int nf = 0; nf < 4; nf++) {
      #pragma unroll
      for (int r = 0; r < 4; r++) {
        int i = iw + mf*16 + ((l >> 4) << 2) + r;
        int e = nf*16 + (l & 15);
        float o = ao[mf][nf][r] + qd[i]*a2[mf][nf][r];
        int s = t*128 + i;
        oh[((size_t)(b*8192 + s))*1024 + h*64 + e] = (h16)o;
      }
    }
  }
}

// ---------------- RMSNorm (per token, fp16 in) -> fp16 --------------------
__global__ __launch_bounds__(256) void k_rms(const h16* __restrict__ o,
                                             const float* __restrict__ rw,
                                             h16* __restrict__ an) {
  const int tid = threadIdx.x;
  const size_t base = (size_t)blockIdx.x * 1024;
  h16x4 hv = *(const h16x4*)(o + base + tid*4);
  float v0 = (float)hv[0], v1 = (float)hv[1], v2 = (float)hv[2], v3 = (float)hv[3];
  float ss = v0*v0 + v1*v1 + v2*v2 + v3*v3;
  #pragma unroll
  for (int off = 32; off > 0; off >>= 1) ss += __shfl_down(ss, off);
  __shared__ float red[4];
  if ((tid & 63) == 0) red[tid >> 6] = ss;
  __syncthreads();
  float f = rsqrtf((red[0]+red[1]+red[2]+red[3]) * (1.0f/1024.0f) + 1e-5f);
  float4 wv = *(const float4*)(rw + tid*4);
  h16x4 r;
  r[0] = (h16)(v0*f*wv.x); r[1] = (h16)(v1*f*wv.y);
  r[2] = (h16)(v2*f*wv.z); r[3] = (h16)(v3*f*wv.w);
  *(h16x4*)(an + base + tid*4) = r;
}

// --------------------------------------------------------------------------
extern "C" void kernel_launch(void* const* d_in, const int* in_sizes, int n_in,
                              void* d_out, int out_size, void* d_ws, size_t ws_size,
                              hipStream_t stream) {
  const float* x  = (const float*)d_in[0];
  const float* fc = (const float*)d_in[1];
  const float* wq = (const float*)d_in[2];
  const float* wk = (const float*)d_in[3];
  const float* wv = (const float*)d_in[4];
  const float* wo = (const float*)d_in[5];
  const float* rw = (const float*)d_in[6];
  float* out = (float*)d_out;

  char* p = (char*)d_ws;
  const size_t SZ = 33554432;
  h16* xh  = (h16*)(p);                  // later reused for An
  h16* qh  = (h16*)(p + SZ);
  h16* kh  = (h16*)(p + 2*SZ);
  h16* vh  = (h16*)(p + 3*SZ);           // later reused for Ph
  h16* kts = (h16*)(p + 4*SZ);
  h16* vt  = (h16*)(p + 5*SZ);
  float* T = (float*)(p + 6*SZ);         // later reused for O (fp16)
  h16* w3  = (h16*)(p + 7*SZ);
  h16* woh = (h16*)(p + 7*SZ + 6291456);

  hipLaunchKernelGGL(k_cvt, dim3(8192), dim3(256), 0, stream, x, xh, 16777216);
  hipLaunchKernelGGL(k_cvt, dim3(512), dim3(256), 0, stream, wq, w3, 1048576);
  hipLaunchKernelGGL(k_cvt, dim3(512), dim3(256), 0, stream, wk, w3 + 1048576, 1048576);
  hipLaunchKernelGGL(k_cvt, dim3(512), dim3(256), 0, stream, wv, w3 + 2097152, 1048576);
  hipLaunchKernelGGL(k_cvt, dim3(512), dim3(256), 0, stream, wo, woh, 1048576);

  hipLaunchKernelGGL(k_qkv, dim3(128, 24), dim3(256), 0, stream, xh, w3, fc, qh, kh, vh);
  hipLaunchKernelGGL(k_tr,  dim3(64, 32), dim3(256), 0, stream, kh, vh, kts, vt);
  hipLaunchKernelGGL(k_kv,  dim3(64, 32), dim3(256), 0, stream, kts, vt, T);
  h16* ph = vh;  // vh dead after k_tr
  hipLaunchKernelGGL(k_scan, dim3(32, 16), dim3(256), 0, stream, T, ph);
  h16* oh = (h16*)T;  // T dead after k_scan; O fp16 (33.5 MB fits exactly)
  hipLaunchKernelGGL(k_att, dim3(64, 32), dim3(256), 0, stream, qh, kh, vt, ph, oh);
  h16* an = xh;  // xh dead after k_qkv
  hipLaunchKernelGGL(k_rms, dim3(16384), dim3(256), 0, stream, oh, rw, an);
  hipLaunchKernelGGL(k_out, dim3(128, 8), dim3(256), 0, stream, an, woh, out);
}

// Round 7
// 348.373 us; speedup vs baseline: 1.1864x; 1.0932x over previous
//
#include <hip/hip_runtime.h>

// B=2 S=8192 E=1024 H=16 D=64 CHUNK=128 NC=64

using h16   = _Float16;
using h16x8 = __attribute__((ext_vector_type(8))) _Float16;
using h16x4 = __attribute__((ext_vector_type(4))) _Float16;
using f32x4 = __attribute__((ext_vector_type(4))) float;

#define MFMA16(a,b,c) __builtin_amdgcn_mfma_f32_16x16x32_f16(a,b,c,0,0,0)

// RoPE on 8 contiguous dims starting at even d0: fp = fc + s*64 + d0,
// fp[2j]=cos, fp[2j+1]=sin for pair (d0+2j, d0+2j+1). Verified identical to
// the r1-proven shfl formulation.
__device__ __forceinline__ h16x8 rope8(h16x8 v, const float* __restrict__ fp) {
  float4 f0 = *(const float4*)fp;
  float4 f1 = *(const float4*)(fp + 4);
  h16x8 o; float x0, x1;
  x0=(float)v[0]; x1=(float)v[1]; o[0]=(h16)(x0*f0.x - x1*f0.y); o[1]=(h16)(x1*f0.x + x0*f0.y);
  x0=(float)v[2]; x1=(float)v[3]; o[2]=(h16)(x0*f0.z - x1*f0.w); o[3]=(h16)(x1*f0.z + x0*f0.w);
  x0=(float)v[4]; x1=(float)v[5]; o[4]=(h16)(x0*f1.x - x1*f1.y); o[5]=(h16)(x1*f1.x + x0*f1.y);
  x0=(float)v[6]; x1=(float)v[7]; o[6]=(h16)(x0*f1.z - x1*f1.w); o[7]=(h16)(x1*f1.z + x0*f1.w);
  return o;
}

// ---------------- fp32 -> fp16 convert (8 elems/thread) ----------------
__global__ __launch_bounds__(256) void k_cvt(const float* __restrict__ s,
                                             h16* __restrict__ d, int n) {
  int i = (blockIdx.x * 256 + threadIdx.x) * 8;
  if (i >= n) return;
  float4 a = *(const float4*)(s + i);
  float4 b = *(const float4*)(s + i + 4);
  h16x8 o;
  o[0]=(h16)a.x; o[1]=(h16)a.y; o[2]=(h16)a.z; o[3]=(h16)a.w;
  o[4]=(h16)b.x; o[5]=(h16)b.y; o[6]=(h16)b.z; o[7]=(h16)b.w;
  *(h16x8*)(d + i) = o;
}

// ---------------- QKV GEMM (M=16384, N=3072, K=1024), natural-layout out ---
// r1-proven mainloop verbatim; epilogue = k_out-style natural [token][e]
// stores (proven pattern), NO RoPE, NO scatter.
__global__ __launch_bounds__(256) void k_qkv(
    const h16* __restrict__ xh, const h16* __restrict__ w3,
    h16* __restrict__ qn, h16* __restrict__ kn, h16* __restrict__ vn)
{
  __shared__ __align__(16) h16 lA[128*64];
  __shared__ __align__(16) h16 lB[128*64];
  const int tid = threadIdx.x;
  const int m0 = blockIdx.x * 128;
  const int nt = blockIdx.y;
  const int n0 = nt * 128;
  const int w = tid >> 6, l = tid & 63;
  const int wr = w >> 1, wc = w & 1;
  const int sr = tid >> 3, sc = tid & 7;
  const int ssl = sc ^ (sr & 7);
  const h16* At = xh + (size_t)m0 * 1024;
  const h16* Bt = w3 + (size_t)n0 * 1024;

  f32x4 acc[4][4] = {};
  h16x8 ra[4], rb[4];
  #pragma unroll
  for (int i = 0; i < 4; i++) {
    ra[i] = *(const h16x8*)(At + (size_t)(i*32+sr)*1024 + sc*8);
    rb[i] = *(const h16x8*)(Bt + (size_t)(i*32+sr)*1024 + sc*8);
  }
  #pragma unroll
  for (int i = 0; i < 4; i++) {
    *(h16x8*)(lA + (i*32+sr)*64 + ssl*8) = ra[i];
    *(h16x8*)(lB + (i*32+sr)*64 + ssl*8) = rb[i];
  }
  __syncthreads();

  for (int kt = 0; kt < 16; ++kt) {
    if (kt < 15) {
      #pragma unroll
      for (int i = 0; i < 4; i++) {
        ra[i] = *(const h16x8*)(At + (size_t)(i*32+sr)*1024 + (kt+1)*64 + sc*8);
        rb[i] = *(const h16x8*)(Bt + (size_t)(i*32+sr)*1024 + (kt+1)*64 + sc*8);
      }
    }
    #pragma unroll
    for (int ks = 0; ks < 2; ++ks) {
      h16x8 af[4], bf[4];
      #pragma unroll
      for (int mf = 0; mf < 4; mf++) {
        int row = wr*64 + mf*16 + (l & 15);
        int slot = (ks*4 + (l >> 4)) ^ (row & 7);
        af[mf] = *(const h16x8*)(lA + row*64 + slot*8);
      }
      #pragma unroll
      for (int nf = 0; nf < 4; nf++) {
        int row = wc*64 + nf*16 + (l & 15);
        int slot = (ks*4 + (l >> 4)) ^ (row & 7);
        bf[nf] = *(const h16x8*)(lB + row*64 + slot*8);
      }
      #pragma unroll
      for (int mf = 0; mf < 4; mf++)
        #pragma unroll
        for (int nf = 0; nf < 4; nf++)
          acc[mf][nf] = MFMA16(af[mf], bf[nf], acc[mf][nf]);
    }
    __syncthreads();
    if (kt < 15) {
      #pragma unroll
      for (int i = 0; i < 4; i++) {
        *(h16x8*)(lA + (i*32+sr)*64 + ssl*8) = ra[i];
        *(h16x8*)(lB + (i*32+sr)*64 + ssl*8) = rb[i];
      }
    }
    __syncthreads();
  }

  // natural-layout epilogue: dst[token][e within proj]
  const int proj = nt >> 3;   // 0=q 1=k 2=v (uniform per block)
  h16* dst = proj == 0 ? qn : (proj == 1 ? kn : vn);
  const int cb = (nt & 7) * 128;
  #pragma unroll
  for (int mf = 0; mf < 4; mf++)
    #pragma unroll
    for (int nf = 0; nf < 4; nf++)
      #pragma unroll
      for (int r = 0; r < 4; r++) {
        int row = wr*64 + mf*16 + ((l >> 4) << 2) + r;
        int col = cb + wc*64 + nf*16 + (l & 15);
        dst[(size_t)(m0 + row)*1024 + col] = (h16)acc[mf][nf][r];
      }
}

// ---------------- final GEMM: out = An @ wo^T (M=16384, N=1024, K=1024) ---
// r1-proven version, verbatim.
__global__ __launch_bounds__(256) void k_out(
    const h16* __restrict__ an, const h16* __restrict__ woh,
    float* __restrict__ out)
{
  __shared__ __align__(16) h16 lA[128*64];
  __shared__ __align__(16) h16 lB[128*64];
  const int tid = threadIdx.x;
  const int m0 = blockIdx.x * 128;
  const int n0 = blockIdx.y * 128;
  const int w = tid >> 6, l = tid & 63;
  const int wr = w >> 1, wc = w & 1;
  const int sr = tid >> 3, sc = tid & 7;
  const int ssl = sc ^ (sr & 7);
  const h16* At = an + (size_t)m0 * 1024;
  const h16* Bt = woh + (size_t)n0 * 1024;

  f32x4 acc[4][4] = {};
  h16x8 ra[4], rb[4];
  #pragma unroll
  for (int i = 0; i < 4; i++) {
    ra[i] = *(const h16x8*)(At + (size_t)(i*32+sr)*1024 + sc*8);
    rb[i] = *(const h16x8*)(Bt + (size_t)(i*32+sr)*1024 + sc*8);
  }
  #pragma unroll
  for (int i = 0; i < 4; i++) {
    *(h16x8*)(lA + (i*32+sr)*64 + ssl*8) = ra[i];
    *(h16x8*)(lB + (i*32+sr)*64 + ssl*8) = rb[i];
  }
  __syncthreads();

  for (int kt = 0; kt < 16; ++kt) {
    if (kt < 15) {
      #pragma unroll
      for (int i = 0; i < 4; i++) {
        ra[i] = *(const h16x8*)(At + (size_t)(i*32+sr)*1024 + (kt+1)*64 + sc*8);
        rb[i] = *(const h16x8*)(Bt + (size_t)(i*32+sr)*1024 + (kt+1)*64 + sc*8);
      }
    }
    #pragma unroll
    for (int ks = 0; ks < 2; ++ks) {
      h16x8 af[4], bf[4];
      #pragma unroll
      for (int mf = 0; mf < 4; mf++) {
        int row = wr*64 + mf*16 + (l & 15);
        int slot = (ks*4 + (l >> 4)) ^ (row & 7);
        af[mf] = *(const h16x8*)(lA + row*64 + slot*8);
      }
      #pragma unroll
      for (int nf = 0; nf < 4; nf++) {
        int row = wc*64 + nf*16 + (l & 15);
        int slot = (ks*4 + (l >> 4)) ^ (row & 7);
        bf[nf] = *(const h16x8*)(lB + row*64 + slot*8);
      }
      #pragma unroll
      for (int mf = 0; mf < 4; mf++)
        #pragma unroll
        for (int nf = 0; nf < 4; nf++)
          acc[mf][nf] = MFMA16(af[mf], bf[nf], acc[mf][nf]);
    }
    __syncthreads();
    if (kt < 15) {
      #pragma unroll
      for (int i = 0; i < 4; i++) {
        *(h16x8*)(lA + (i*32+sr)*64 + ssl*8) = ra[i];
        *(h16x8*)(lB + (i*32+sr)*64 + ssl*8) = rb[i];
      }
    }
    __syncthreads();
  }
  #pragma unroll
  for (int mf = 0; mf < 4; mf++)
    #pragma unroll
    for (int nf = 0; nf < 4; nf++)
      #pragma unroll
      for (int r = 0; r < 4; r++) {
        int row = wr*64 + mf*16 + ((l >> 4) << 2) + r;
        int col = wc*64 + nf*16 + (l & 15);
        out[(size_t)(m0 + row)*1024 + n0 + col] = acc[mf][nf][r];
      }
}

// ------- transpose from natural layout: K->RoPE->(K^T*k_dec), V->V^T ------
__global__ __launch_bounds__(256) void k_tr(
    const h16* __restrict__ kn, const h16* __restrict__ vn,
    const float* __restrict__ fc,
    h16* __restrict__ kts, h16* __restrict__ vt)
{
  __shared__ __align__(16) h16 tl[128*64];
  __shared__ float dt[128];
  const int tid = threadIdx.x;
  const int st = blockIdx.x;   // chunk 0..63
  const int bh = blockIdx.y;   // 0..31
  const int b = bh >> 4, h = bh & 15;
  if (tid < 128) {
    float slope = exp2f(-0.5f * (float)(h + 1));
    dt[tid] = expf(-slope * (float)(127 - tid));
  }
  const size_t ibase = ((size_t)(b*8192 + st*128))*1024 + h*64;
  const size_t obase = (size_t)bh*64*8192 + st*128;
  const int cr = tid >> 3, c8 = tid & 7;

  for (int which = 0; which < 2; ++which) {
    const h16* src = which ? vn : kn;
    h16* dstp = which ? vt : kts;
    __syncthreads();
    #pragma unroll
    for (int i = 0; i < 4; i++) {
      int r = i*32 + cr;
      h16x8 v = *(const h16x8*)(src + ibase + (size_t)r*1024 + c8*8);
      if (!which) v = rope8(v, fc + (size_t)(st*128 + r)*64 + c8*8);
      int slot = (c8 + ((r >> 3) & 7)) & 7;
      *(h16x8*)(tl + r*64 + slot*8) = v;
    }
    __syncthreads();
    #pragma unroll
    for (int i = 0; i < 4; i++) {
      int chunk = i*256 + tid;
      int d = chunk >> 4;
      int j8 = chunk & 15;
      h16x8 o;
      #pragma unroll
      for (int jj = 0; jj < 8; jj++) {
        int c = j8*8 + jj;
        int pos = (d + ((c >> 3) & 7)*8) & 63;
        float fv = (float)tl[c*64 + pos];
        if (!which) fv *= dt[c];
        o[jj] = (h16)fv;
      }
      *(h16x8*)(dstp + obase + (size_t)d*8192 + j8*8) = o;
    }
  }
}

// ---------------- per-chunk KV^T state ------------------------------------
__global__ __launch_bounds__(256) void k_kv(
    const h16* __restrict__ kts, const h16* __restrict__ vt,
    float* __restrict__ T)
{
  const int tid = threadIdx.x;
  const int t = blockIdx.x;
  const int bh = blockIdx.y;
  const int w = tid >> 6, l = tid & 63;
  const h16* vb = vt  + (size_t)bh*64*8192 + t*128;
  const h16* kb = kts + (size_t)bh*64*8192 + t*128;
  f32x4 acc[4] = {};
  h16x8 a[4];
  #pragma unroll
  for (int ks = 0; ks < 4; ks++)
    a[ks] = *(const h16x8*)(vb + (size_t)(w*16 + (l & 15))*8192 + ks*32 + (l >> 4)*8);
  #pragma unroll
  for (int nf = 0; nf < 4; nf++) {
    #pragma unroll
    for (int ks = 0; ks < 4; ks++) {
      h16x8 bfr = *(const h16x8*)(kb + (size_t)(nf*16 + (l & 15))*8192 + ks*32 + (l >> 4)*8);
      acc[nf] = MFMA16(a[ks], bfr, acc[nf]);
    }
  }
  float* Tb = T + ((size_t)bh*64 + t)*4096;
  #pragma unroll
  for (int nf = 0; nf < 4; nf++)
    #pragma unroll
    for (int r = 0; r < 4; r++) {
      int e = w*16 + ((l >> 4) << 2) + r;
      int d = nf*16 + (l & 15);
      Tb[e*64 + d] = acc[nf][r];
    }
}

// ---------------- decay prefix scan over chunks (1 elem/thread) -----------
__global__ __launch_bounds__(256) void k_scan(const float* __restrict__ T,
                                              h16* __restrict__ ph) {
  const int bh = blockIdx.x;
  const int j  = blockIdx.y * 256 + threadIdx.x;
  const int h = bh & 15;
  const float cdec = expf(-exp2f(-0.5f*(float)(h+1)) * 128.0f);
  const float* Tb = T + (size_t)bh*64*4096 + j;
  h16* pb = ph + (size_t)bh*64*4096 + j;
  float run = 0.f;
  for (int t = 0; t < 64; t++) {
    float kv = Tb[(size_t)t*4096];
    pb[(size_t)t*4096] = (h16)run;
    run = cdec*run + kv;
  }
}

// ------- per-chunk attention output (nat Q/K + on-the-fly RoPE) -----------
__global__ __launch_bounds__(256) void k_att(
    const h16* __restrict__ qn, const h16* __restrict__ kn,
    const float* __restrict__ fc,
    const h16* __restrict__ vt, const h16* __restrict__ ph,
    h16* __restrict__ oh)
{
  __shared__ __align__(16) h16 P[128*144];
  __shared__ float dt[128], qd[128];
  const int tid = threadIdx.x;
  const int t = blockIdx.x;
  const int bh = blockIdx.y;
  const int b = bh >> 4, h = bh & 15;
  if (tid < 128) {
    float slope = exp2f(-0.5f*(float)(h+1));
    dt[tid] = expf(-slope*(float)tid);
    qd[tid] = expf(-slope*(float)(tid+1));
  }
  __syncthreads();
  const int w = tid >> 6, l = tid & 63;
  const int iw = w * 32;
  const h16* qb = qn + ((size_t)(b*8192 + t*128))*1024 + h*64;
  const h16* kb = kn + ((size_t)(b*8192 + t*128))*1024 + h*64;
  const h16* vb = vt + (size_t)bh*64*8192 + t*128;
  const h16* pb = ph + ((size_t)bh*64 + t)*4096;
  const float* fcb = fc + (size_t)(t*128)*64;

  h16x8 aq[2][2];
  #pragma unroll
  for (int mf = 0; mf < 2; mf++)
    #pragma unroll
    for (int ks = 0; ks < 2; ks++) {
      int row = iw + mf*16 + (l & 15);
      int d0 = ks*32 + (l >> 4)*8;
      aq[mf][ks] = rope8(*(const h16x8*)(qb + (size_t)row*1024 + d0),
                         fcb + (size_t)row*64 + d0);
    }

  // QK^T — causal: tile (rows iw..iw+31) needs only cols j <= iw+31
  f32x4 sc[2][8] = {};
  #pragma unroll
  for (int nf = 0; nf < 8; nf++) {
    if (nf*16 <= iw + 31) {
      #pragma unroll
      for (int ks = 0; ks < 2; ks++) {
        int row = nf*16 + (l & 15);
        int d0 = ks*32 + (l >> 4)*8;
        h16x8 bk = rope8(*(const h16x8*)(kb + (size_t)row*1024 + d0),
                         fcb + (size_t)row*64 + d0);
        sc[0][nf] = MFMA16(aq[0][ks], bk, sc[0][nf]);
        sc[1][nf] = MFMA16(aq[1][ks], bk, sc[1][nf]);
      }
    }
  }
  #pragma unroll
  for (int mf = 0; mf < 2; mf++) {
    #pragma unroll
    for (int nf = 0; nf < 8; nf++) {
      #pragma unroll
      for (int r = 0; r < 4; r++) {
        int i = iw + mf*16 + ((l >> 4) << 2) + r;
        int j = nf*16 + (l & 15);
        int diff = i - j;
        float v = diff >= 0 ? sc[mf][nf][r]*dt[diff] : 0.f;
        P[i*144 + j] = (h16)v;
      }
    }
  }
  f32x4 ao[2][4] = {};
  #pragma unroll
  for (int kc = 0; kc < 4; kc++) {
    h16x8 ap0 = *(const h16x8*)(P + (size_t)(iw + (l & 15))*144 + kc*32 + (l >> 4)*8);
    h16x8 ap1 = *(const h16x8*)(P + (size_t)(iw + 16 + (l & 15))*144 + kc*32 + (l >> 4)*8);
    #pragma unroll
    for (int nf = 0; nf < 4; nf++) {
      h16x8 bv = *(const h16x8*)(vb + (size_t)(nf*16 + (l & 15))*8192 + kc*32 + (l >> 4)*8);
      ao[0][nf] = MFMA16(ap0, bv, ao[0][nf]);
      ao[1][nf] = MFMA16(ap1, bv, ao[1][nf]);
    }
  }
  f32x4 a2[2][4] = {};
  #pragma unroll
  for (int ks = 0; ks < 2; ks++) {
    #pragma unroll
    for (int nf = 0; nf < 4; nf++) {
      h16x8 bs = *(const h16x8*)(pb + (size_t)(nf*16 + (l & 15))*64 + ks*32 + (l >> 4)*8);
      a2[0][nf] = MFMA16(aq[0][ks], bs, a2[0][nf]);
      a2[1][nf] = MFMA16(aq[1][ks], bs, a2[1][nf]);
    }
  }
  #pragma unroll
  for (int mf = 0; mf < 2; mf++) {
    #pragma unroll
    for (int nf = 0; nf < 4; nf++) {
      #pragma unroll
      for (int r = 0; r < 4; r++) {
        int i = iw + mf*16 + ((l >> 4) << 2) + r;
        int e = nf*16 + (l & 15);
        float o = ao[mf][nf][r] + qd[i]*a2[mf][nf][r];
        int s = t*128 + i;
        oh[((size_t)(b*8192 + s))*1024 + h*64 + e] = (h16)o;
      }
    }
  }
}

// ---------------- RMSNorm (per token, fp16 in) -> fp16 --------------------
__global__ __launch_bounds__(256) void k_rms(const h16* __restrict__ o,
                                             const float* __restrict__ rw,
                                             h16* __restrict__ an) {
  const int tid = threadIdx.x;
  const size_t base = (size_t)blockIdx.x * 1024;
  h16x4 hv = *(const h16x4*)(o + base + tid*4);
  float v0 = (float)hv[0], v1 = (float)hv[1], v2 = (float)hv[2], v3 = (float)hv[3];
  float ss = v0*v0 + v1*v1 + v2*v2 + v3*v3;
  #pragma unroll
  for (int off = 32; off > 0; off >>= 1) ss += __shfl_down(ss, off);
  __shared__ float red[4];
  if ((tid & 63) == 0) red[tid >> 6] = ss;
  __syncthreads();
  float f = rsqrtf((red[0]+red[1]+red[2]+red[3]) * (1.0f/1024.0f) + 1e-5f);
  float4 wv = *(const float4*)(rw + tid*4);
  h16x4 r;
  r[0] = (h16)(v0*f*wv.x); r[1] = (h16)(v1*f*wv.y);
  r[2] = (h16)(v2*f*wv.z); r[3] = (h16)(v3*f*wv.w);
  *(h16x4*)(an + base + tid*4) = r;
}

// --------------------------------------------------------------------------
extern "C" void kernel_launch(void* const* d_in, const int* in_sizes, int n_in,
                              void* d_out, int out_size, void* d_ws, size_t ws_size,
                              hipStream_t stream) {
  const float* x  = (const float*)d_in[0];
  const float* fc = (const float*)d_in[1];
  const float* wq = (const float*)d_in[2];
  const float* wk = (const float*)d_in[3];
  const float* wv = (const float*)d_in[4];
  const float* wo = (const float*)d_in[5];
  const float* rw = (const float*)d_in[6];
  float* out = (float*)d_out;

  char* p = (char*)d_ws;
  const size_t SZ = 33554432;
  h16* xh  = (h16*)(p);                  // later reused for An
  h16* vn  = (h16*)(p + 3*SZ);           // V natural; later reused for Ph
  h16* kts = (h16*)(p + 4*SZ);
  h16* vt  = (h16*)(p + 5*SZ);
  float* T = (float*)(p + 6*SZ);         // later reused for O (fp16)
  h16* w3  = (h16*)(p + 7*SZ);
  h16* woh = (h16*)(p + 7*SZ + 6291456);
  // Q/K natural layout live in d_out (free until k_out overwrites it)
  h16* qn = (h16*)out;
  h16* kn = (h16*)out + 16777216;

  hipLaunchKernelGGL(k_cvt, dim3(8192), dim3(256), 0, stream, x, xh, 16777216);
  hipLaunchKernelGGL(k_cvt, dim3(512), dim3(256), 0, stream, wq, w3, 1048576);
  hipLaunchKernelGGL(k_cvt, dim3(512), dim3(256), 0, stream, wk, w3 + 1048576, 1048576);
  hipLaunchKernelGGL(k_cvt, dim3(512), dim3(256), 0, stream, wv, w3 + 2097152, 1048576);
  hipLaunchKernelGGL(k_cvt, dim3(512), dim3(256), 0, stream, wo, woh, 1048576);

  hipLaunchKernelGGL(k_qkv, dim3(128, 24), dim3(256), 0, stream, xh, w3, qn, kn, vn);
  hipLaunchKernelGGL(k_tr,  dim3(64, 32), dim3(256), 0, stream, kn, vn, fc, kts, vt);
  hipLaunchKernelGGL(k_kv,  dim3(64, 32), dim3(256), 0, stream, kts, vt, T);
  h16* ph = vn;  // vn dead after k_tr
  hipLaunchKernelGGL(k_scan, dim3(32, 16), dim3(256), 0, stream, T, ph);
  h16* oh = (h16*)T;  // T dead after k_scan
  hipLaunchKernelGGL(k_att, dim3(64, 32), dim3(256), 0, stream, qn, kn, fc, vt, ph, oh);
  h16* an = xh;  // xh dead after k_qkv
  hipLaunchKernelGGL(k_rms, dim3(16384), dim3(256), 0, stream, oh, rw, an);
  hipLaunchKernelGGL(k_out, dim3(128, 8), dim3(256), 0, stream, an, woh, out);
}

// Round 8
// 318.189 us; speedup vs baseline: 1.2990x; 1.0949x over previous
//
#include <hip/hip_runtime.h>

// B=2 S=8192 E=1024 H=16 D=64 CHUNK=128 NC=64

using h16   = _Float16;
using h16x8 = __attribute__((ext_vector_type(8))) _Float16;
using h16x4 = __attribute__((ext_vector_type(4))) _Float16;
using f32x4 = __attribute__((ext_vector_type(4))) float;

#define MFMA16(a,b,c) __builtin_amdgcn_mfma_f32_16x16x32_f16(a,b,c,0,0,0)

#define GLOAD16(gp, lp) __builtin_amdgcn_global_load_lds( \
    (const __attribute__((address_space(1))) void*)(gp),  \
    (__attribute__((address_space(3))) void*)(lp), 16, 0, 0)

// RoPE on 8 contiguous dims starting at even d0: fp = fc + s*64 + d0.
__device__ __forceinline__ h16x8 rope8(h16x8 v, const float* __restrict__ fp) {
  float4 f0 = *(const float4*)fp;
  float4 f1 = *(const float4*)(fp + 4);
  h16x8 o; float x0, x1;
  x0=(float)v[0]; x1=(float)v[1]; o[0]=(h16)(x0*f0.x - x1*f0.y); o[1]=(h16)(x1*f0.x + x0*f0.y);
  x0=(float)v[2]; x1=(float)v[3]; o[2]=(h16)(x0*f0.z - x1*f0.w); o[3]=(h16)(x1*f0.z + x0*f0.w);
  x0=(float)v[4]; x1=(float)v[5]; o[4]=(h16)(x0*f1.x - x1*f1.y); o[5]=(h16)(x1*f1.x + x0*f1.y);
  x0=(float)v[6]; x1=(float)v[7]; o[6]=(h16)(x0*f1.z - x1*f1.w); o[7]=(h16)(x1*f1.z + x0*f1.w);
  return o;
}

// ---------------- fp32 -> fp16 convert (8 elems/thread) ----------------
__global__ __launch_bounds__(256) void k_cvt(const float* __restrict__ s,
                                             h16* __restrict__ d, int n) {
  int i = (blockIdx.x * 256 + threadIdx.x) * 8;
  if (i >= n) return;
  float4 a = *(const float4*)(s + i);
  float4 b = *(const float4*)(s + i + 4);
  h16x8 o;
  o[0]=(h16)a.x; o[1]=(h16)a.y; o[2]=(h16)a.z; o[3]=(h16)a.w;
  o[4]=(h16)b.x; o[5]=(h16)b.y; o[6]=(h16)b.z; o[7]=(h16)b.w;
  *(h16x8*)(d + i) = o;
}

// ===== 256x256 counted-vmcnt GEMM mainloop =====
// BK=64, 8 waves (2M x 4N), per-wave out 128x64. LDS 128 KiB:
//   lA = smem       + buf*32768 + half*16384   (half: rows 0-127 / 128-255)
//   lB = smem+65536 + buf*32768 + half*16384
// Half-tile rows are 128 B; granule XOR swizzle slot^(row&7) applied on the
// GLOBAL source (gload_lds writes linearly) and on the ds_read side (proven
// r1/r7 pattern). Per K-tile body:
//   24x ds_read -> lgkmcnt(0) -> barrier -> stage(t+2) ->
//   setprio(1) 64x MFMA setprio(0) -> vmcnt(8) -> barrier
// vmcnt(8) = one K-tile's 8 gloads may stay in flight (2-tile lookahead).
__device__ __forceinline__ void gemm256_loop(
    const h16* __restrict__ At, const h16* __restrict__ Bt,
    char* smem, int w, int l, f32x4 (&acc)[8][4])
{
  char* lA = smem;
  char* lB = smem + 65536;
  const int wr = w >> 2, wc = w & 3;
  const int rl = l >> 3;
  const int sl8 = ((l & 7) ^ rl) * 8;          // logical slot (h16 units)

  auto stage = [&](int kt) {
    const int kb = (kt & 1) * 32768;
    #pragma unroll
    for (int half = 0; half < 2; half++) {
      #pragma unroll
      for (int c = 0; c < 2; c++) {
        const int r = half*128 + (c*8 + w)*8 + rl;
        const int dof = kb + half*16384 + (c*8 + w)*1024;
        GLOAD16(At + (size_t)r*1024 + kt*64 + sl8, lA + dof);
        GLOAD16(Bt + (size_t)r*1024 + kt*64 + sl8, lB + dof);
      }
    }
  };

  const int foff0 = (((l >> 4)    ) ^ (l & 7)) * 16;   // bytes
  const int foff1 = (((l >> 4) + 4) ^ (l & 7)) * 16;
  const int abyte = wr*16384 + (l & 15)*128;
  const int bbyte = (wc >> 1)*16384 + ((wc & 1)*64 + (l & 15))*128;

  stage(0); stage(1);
  asm volatile("s_waitcnt vmcnt(8)" ::: "memory");   // tile0 landed
  __builtin_amdgcn_sched_barrier(0);
  __builtin_amdgcn_s_barrier();

  for (int t = 0; t < 16; ++t) {
    const int kb = (t & 1) * 32768;
    const char* aB = lA + kb + abyte;
    const char* bB = lB + kb + bbyte;
    h16x8 af0[8], af1[8], bf0[4], bf1[4];
    #pragma unroll
    for (int mf = 0; mf < 8; mf++) {
      af0[mf] = *(const h16x8*)(aB + mf*2048 + foff0);
      af1[mf] = *(const h16x8*)(aB + mf*2048 + foff1);
    }
    #pragma unroll
    for (int nf = 0; nf < 4; nf++) {
      bf0[nf] = *(const h16x8*)(bB + nf*2048 + foff0);
      bf1[nf] = *(const h16x8*)(bB + nf*2048 + foff1);
    }
    asm volatile("s_waitcnt lgkmcnt(0)" ::: "memory");  // my reads done
    __builtin_amdgcn_sched_barrier(0);
    __builtin_amdgcn_s_barrier();                       // all waves done -> region free
    if (t < 14) stage(t + 2);                           // overwrite buf[t&1] safely
    __builtin_amdgcn_s_setprio(1);
    #pragma unroll
    for (int mf = 0; mf < 8; mf++)
      #pragma unroll
      for (int nf = 0; nf < 4; nf++)
        acc[mf][nf] = MFMA16(af0[mf], bf0[nf], acc[mf][nf]);
    #pragma unroll
    for (int mf = 0; mf < 8; mf++)
      #pragma unroll
      for (int nf = 0; nf < 4; nf++)
        acc[mf][nf] = MFMA16(af1[mf], bf1[nf], acc[mf][nf]);
    __builtin_amdgcn_s_setprio(0);
    if (t < 14)       asm volatile("s_waitcnt vmcnt(8)" ::: "memory");  // t+1 landed
    else if (t == 14) asm volatile("s_waitcnt vmcnt(0)" ::: "memory");  // t15 landed
    if (t < 15) {
      __builtin_amdgcn_sched_barrier(0);
      __builtin_amdgcn_s_barrier();
    }
  }
}

// ---------------- QKV GEMM (M=16384, N=3072, K=1024), natural-layout out ---
__global__ __launch_bounds__(512, 2) void k_qkv(
    const h16* __restrict__ xh, const h16* __restrict__ w3,
    h16* __restrict__ qn, h16* __restrict__ kn, h16* __restrict__ vn)
{
  extern __shared__ __align__(16) char smem[];   // 128 KiB
  const int tid = threadIdx.x;
  const int w = tid >> 6, l = tid & 63;
  const int m0 = blockIdx.x * 256;
  const int nt = blockIdx.y;                     // 0..11
  const int wr = w >> 2, wc = w & 3;

  f32x4 acc[8][4] = {};
  gemm256_loop(xh + (size_t)m0*1024, w3 + (size_t)(nt*256)*1024, smem, w, l, acc);

  const int proj = nt >> 2;   // 0=q 1=k 2=v (uniform per block)
  h16* dst = proj == 0 ? qn : (proj == 1 ? kn : vn);
  const int cb = (nt & 3)*256 + wc*64;
  #pragma unroll
  for (int mf = 0; mf < 8; mf++)
    #pragma unroll
    for (int nf = 0; nf < 4; nf++)
      #pragma unroll
      for (int r = 0; r < 4; r++) {
        int row = wr*128 + mf*16 + ((l >> 4) << 2) + r;
        int col = cb + nf*16 + (l & 15);
        dst[(size_t)(m0 + row)*1024 + col] = (h16)acc[mf][nf][r];
      }
}

// ---------------- final GEMM: out = An @ wo^T (M=16384, N=1024, K=1024) ---
__global__ __launch_bounds__(512, 2) void k_out(
    const h16* __restrict__ an, const h16* __restrict__ woh,
    float* __restrict__ out)
{
  extern __shared__ __align__(16) char smem[];
  const int tid = threadIdx.x;
  const int w = tid >> 6, l = tid & 63;
  const int m0 = blockIdx.x * 256;
  const int n0 = blockIdx.y * 256;
  const int wr = w >> 2, wc = w & 3;

  f32x4 acc[8][4] = {};
  gemm256_loop(an + (size_t)m0*1024, woh + (size_t)n0*1024, smem, w, l, acc);

  #pragma unroll
  for (int mf = 0; mf < 8; mf++)
    #pragma unroll
    for (int nf = 0; nf < 4; nf++)
      #pragma unroll
      for (int r = 0; r < 4; r++) {
        int row = wr*128 + mf*16 + ((l >> 4) << 2) + r;
        int col = n0 + wc*64 + nf*16 + (l & 15);
        out[(size_t)(m0 + row)*1024 + col] = acc[mf][nf][r];
      }
}

// ------- transpose from natural layout: K->RoPE->(K^T*k_dec), V->V^T ------
__global__ __launch_bounds__(256) void k_tr(
    const h16* __restrict__ kn, const h16* __restrict__ vn,
    const float* __restrict__ fc,
    h16* __restrict__ kts, h16* __restrict__ vt)
{
  __shared__ __align__(16) h16 tl[128*64];
  __shared__ float dt[128];
  const int tid = threadIdx.x;
  const int st = blockIdx.x;   // chunk 0..63
  const int bh = blockIdx.y;   // 0..31
  const int b = bh >> 4, h = bh & 15;
  if (tid < 128) {
    float slope = exp2f(-0.5f * (float)(h + 1));
    dt[tid] = expf(-slope * (float)(127 - tid));
  }
  const size_t ibase = ((size_t)(b*8192 + st*128))*1024 + h*64;
  const size_t obase = (size_t)bh*64*8192 + st*128;
  const int cr = tid >> 3, c8 = tid & 7;

  for (int which = 0; which < 2; ++which) {
    const h16* src = which ? vn : kn;
    h16* dstp = which ? vt : kts;
    __syncthreads();
    #pragma unroll
    for (int i = 0; i < 4; i++) {
      int r = i*32 + cr;
      h16x8 v = *(const h16x8*)(src + ibase + (size_t)r*1024 + c8*8);
      if (!which) v = rope8(v, fc + (size_t)(st*128 + r)*64 + c8*8);
      int slot = (c8 + ((r >> 3) & 7)) & 7;
      *(h16x8*)(tl + r*64 + slot*8) = v;
    }
    __syncthreads();
    #pragma unroll
    for (int i = 0; i < 4; i++) {
      int chunk = i*256 + tid;
      int d = chunk >> 4;
      int j8 = chunk & 15;
      h16x8 o;
      #pragma unroll
      for (int jj = 0; jj < 8; jj++) {
        int c = j8*8 + jj;
        int pos = (d + ((c >> 3) & 7)*8) & 63;
        float fv = (float)tl[c*64 + pos];
        if (!which) fv *= dt[c];
        o[jj] = (h16)fv;
      }
      *(h16x8*)(dstp + obase + (size_t)d*8192 + j8*8) = o;
    }
  }
}

// ---------------- per-chunk KV^T state ------------------------------------
__global__ __launch_bounds__(256) void k_kv(
    const h16* __restrict__ kts, const h16* __restrict__ vt,
    float* __restrict__ T)
{
  const int tid = threadIdx.x;
  const int t = blockIdx.x;
  const int bh = blockIdx.y;
  const int w = tid >> 6, l = tid & 63;
  const h16* vb = vt  + (size_t)bh*64*8192 + t*128;
  const h16* kb = kts + (size_t)bh*64*8192 + t*128;
  f32x4 acc[4] = {};
  h16x8 a[4];
  #pragma unroll
  for (int ks = 0; ks < 4; ks++)
    a[ks] = *(const h16x8*)(vb + (size_t)(w*16 + (l & 15))*8192 + ks*32 + (l >> 4)*8);
  #pragma unroll
  for (int nf = 0; nf < 4; nf++) {
    #pragma unroll
    for (int ks = 0; ks < 4; ks++) {
      h16x8 bfr = *(const h16x8*)(kb + (size_t)(nf*16 + (l & 15))*8192 + ks*32 + (l >> 4)*8);
      acc[nf] = MFMA16(a[ks], bfr, acc[nf]);
    }
  }
  float* Tb = T + ((size_t)bh*64 + t)*4096;
  #pragma unroll
  for (int nf = 0; nf < 4; nf++)
    #pragma unroll
    for (int r = 0; r < 4; r++) {
      int e = w*16 + ((l >> 4) << 2) + r;
      int d = nf*16 + (l & 15);
      Tb[e*64 + d] = acc[nf][r];
    }
}

// ---------------- decay prefix scan over chunks (1 elem/thread) -----------
__global__ __launch_bounds__(256) void k_scan(const float* __restrict__ T,
                                              h16* __restrict__ ph) {
  const int bh = blockIdx.x;
  const int j  = blockIdx.y * 256 + threadIdx.x;
  const int h = bh & 15;
  const float cdec = expf(-exp2f(-0.5f*(float)(h+1)) * 128.0f);
  const float* Tb = T + (size_t)bh*64*4096 + j;
  h16* pb = ph + (size_t)bh*64*4096 + j;
  float run = 0.f;
  for (int t = 0; t < 64; t++) {
    float kv = Tb[(size_t)t*4096];
    pb[(size_t)t*4096] = (h16)run;
    run = cdec*run + kv;
  }
}

// ------- per-chunk attention output (nat Q/K + on-the-fly RoPE) -----------
__global__ __launch_bounds__(256) void k_att(
    const h16* __restrict__ qn, const h16* __restrict__ kn,
    const float* __restrict__ fc,
    const h16* __restrict__ vt, const h16* __restrict__ ph,
    h16* __restrict__ oh)
{
  __shared__ __align__(16) h16 P[128*144];
  __shared__ float dt[128], qd[128];
  const int tid = threadIdx.x;
  const int t = blockIdx.x;
  const int bh = blockIdx.y;
  const int b = bh >> 4, h = bh & 15;
  if (tid < 128) {
    float slope = exp2f(-0.5f*(float)(h+1));
    dt[tid] = expf(-slope*(float)tid);
    qd[tid] = expf(-slope*(float)(tid+1));
  }
  __syncthreads();
  const int w = tid >> 6, l = tid & 63;
  const int iw = w * 32;
  const h16* qb = qn + ((size_t)(b*8192 + t*128))*1024 + h*64;
  const h16* kb = kn + ((size_t)(b*8192 + t*128))*1024 + h*64;
  const h16* vb = vt + (size_t)bh*64*8192 + t*128;
  const h16* pb = ph + ((size_t)bh*64 + t)*4096;
  const float* fcb = fc + (size_t)(t*128)*64;

  h16x8 aq[2][2];
  #pragma unroll
  for (int mf = 0; mf < 2; mf++)
    #pragma unroll
    for (int ks = 0; ks < 2; ks++) {
      int row = iw + mf*16 + (l & 15);
      int d0 = ks*32 + (l >> 4)*8;
      aq[mf][ks] = rope8(*(const h16x8*)(qb + (size_t)row*1024 + d0),
                         fcb + (size_t)row*64 + d0);
    }

  // QK^T — causal: tile (rows iw..iw+31) needs only cols j <= iw+31
  f32x4 sc[2][8] = {};
  #pragma unroll
  for (int nf = 0; nf < 8; nf++) {
    if (nf*16 <= iw + 31) {
      #pragma unroll
      for (int ks = 0; ks < 2; ks++) {
        int row = nf*16 + (l & 15);
        int d0 = ks*32 + (l >> 4)*8;
        h16x8 bk = rope8(*(const h16x8*)(kb + (size_t)row*1024 + d0),
                         fcb + (size_t)row*64 + d0);
        sc[0][nf] = MFMA16(aq[0][ks], bk, sc[0][nf]);
        sc[1][nf] = MFMA16(aq[1][ks], bk, sc[1][nf]);
      }
    }
  }
  #pragma unroll
  for (int mf = 0; mf < 2; mf++) {
    #pragma unroll
    for (int nf = 0; nf < 8; nf++) {
      #pragma unroll
      for (int r = 0; r < 4; r++) {
        int i = iw + mf*16 + ((l >> 4) << 2) + r;
        int j = nf*16 + (l & 15);
        int diff = i - j;
        float v = diff >= 0 ? sc[mf][nf][r]*dt[diff] : 0.f;
        P[i*144 + j] = (h16)v;
      }
    }
  }
  f32x4 ao[2][4] = {};
  #pragma unroll
  for (int kc = 0; kc < 4; kc++) {
    h16x8 ap0 = *(const h16x8*)(P + (size_t)(iw + (l & 15))*144 + kc*32 + (l >> 4)*8);
    h16x8 ap1 = *(const h16x8*)(P + (size_t)(iw + 16 + (l & 15))*144 + kc*32 + (l >> 4)*8);
    #pragma unroll
    for (int nf = 0; nf < 4; nf++) {
      h16x8 bv = *(const h16x8*)(vb + (size_t)(nf*16 + (l & 15))*8192 + kc*32 + (l >> 4)*8);
      ao[0][nf] = MFMA16(ap0, bv, ao[0][nf]);
      ao[1][nf] = MFMA16(ap1, bv, ao[1][nf]);
    }
  }
  f32x4 a2[2][4] = {};
  #pragma unroll
  for (int ks = 0; ks < 2; ks++) {
    #pragma unroll
    for (int nf = 0; nf < 4; nf++) {
      h16x8 bs = *(const h16x8*)(pb + (size_t)(nf*16 + (l & 15))*64 + ks*32 + (l >> 4)*8);
      a2[0][nf] = MFMA16(aq[0][ks], bs, a2[0][nf]);
      a2[1][nf] = MFMA16(aq[1][ks], bs, a2[1][nf]);
    }
  }
  #pragma unroll
  for (int mf = 0; mf < 2; mf++) {
    #pragma unroll
    for (int nf = 0; nf < 4; nf++) {
      #pragma unroll
      for (int r = 0; r < 4; r++) {
        int i = iw + mf*16 + ((l >> 4) << 2) + r;
        int e = nf*16 + (l & 15);
        float o = ao[mf][nf][r] + qd[i]*a2[mf][nf][r];
        int s = t*128 + i;
        oh[((size_t)(b*8192 + s))*1024 + h*64 + e] = (h16)o;
      }
    }
  }
}

// ---------------- RMSNorm (per token, fp16 in) -> fp16 --------------------
__global__ __launch_bounds__(256) void k_rms(const h16* __restrict__ o,
                                             const float* __restrict__ rw,
                                             h16* __restrict__ an) {
  const int tid = threadIdx.x;
  const size_t base = (size_t)blockIdx.x * 1024;
  h16x4 hv = *(const h16x4*)(o + base + tid*4);
  float v0 = (float)hv[0], v1 = (float)hv[1], v2 = (float)hv[2], v3 = (float)hv[3];
  float ss = v0*v0 + v1*v1 + v2*v2 + v3*v3;
  #pragma unroll
  for (int off = 32; off > 0; off >>= 1) ss += __shfl_down(ss, off);
  __shared__ float red[4];
  if ((tid & 63) == 0) red[tid >> 6] = ss;
  __syncthreads();
  float f = rsqrtf((red[0]+red[1]+red[2]+red[3]) * (1.0f/1024.0f) + 1e-5f);
  float4 wv = *(const float4*)(rw + tid*4);
  h16x4 r;
  r[0] = (h16)(v0*f*wv.x); r[1] = (h16)(v1*f*wv.y);
  r[2] = (h16)(v2*f*wv.z); r[3] = (h16)(v3*f*wv.w);
  *(h16x4*)(an + base + tid*4) = r;
}

// --------------------------------------------------------------------------
extern "C" void kernel_launch(void* const* d_in, const int* in_sizes, int n_in,
                              void* d_out, int out_size, void* d_ws, size_t ws_size,
                              hipStream_t stream) {
  const float* x  = (const float*)d_in[0];
  const float* fc = (const float*)d_in[1];
  const float* wq = (const float*)d_in[2];
  const float* wk = (const float*)d_in[3];
  const float* wv = (const float*)d_in[4];
  const float* wo = (const float*)d_in[5];
  const float* rw = (const float*)d_in[6];
  float* out = (float*)d_out;

  char* p = (char*)d_ws;
  const size_t SZ = 33554432;
  h16* xh  = (h16*)(p);                  // later reused for An
  h16* vn  = (h16*)(p + 3*SZ);           // V natural; later reused for Ph
  h16* kts = (h16*)(p + 4*SZ);
  h16* vt  = (h16*)(p + 5*SZ);
  float* T = (float*)(p + 6*SZ);         // later reused for O (fp16)
  h16* w3  = (h16*)(p + 7*SZ);
  h16* woh = (h16*)(p + 7*SZ + 6291456);
  // Q/K natural layout live in d_out (free until k_out overwrites it)
  h16* qn = (h16*)out;
  h16* kn = (h16*)out + 16777216;

  (void)hipFuncSetAttribute((const void*)k_qkv, hipFuncAttributeMaxDynamicSharedMemorySize, 131072);
  (void)hipFuncSetAttribute((const void*)k_out, hipFuncAttributeMaxDynamicSharedMemorySize, 131072);

  hipLaunchKernelGGL(k_cvt, dim3(8192), dim3(256), 0, stream, x, xh, 16777216);
  hipLaunchKernelGGL(k_cvt, dim3(512), dim3(256), 0, stream, wq, w3, 1048576);
  hipLaunchKernelGGL(k_cvt, dim3(512), dim3(256), 0, stream, wk, w3 + 1048576, 1048576);
  hipLaunchKernelGGL(k_cvt, dim3(512), dim3(256), 0, stream, wv, w3 + 2097152, 1048576);
  hipLaunchKernelGGL(k_cvt, dim3(512), dim3(256), 0, stream, wo, woh, 1048576);

  hipLaunchKernelGGL(k_qkv, dim3(64, 12), dim3(512), 131072, stream, xh, w3, qn, kn, vn);
  hipLaunchKernelGGL(k_tr,  dim3(64, 32), dim3(256), 0, stream, kn, vn, fc, kts, vt);
  hipLaunchKernelGGL(k_kv,  dim3(64, 32), dim3(256), 0, stream, kts, vt, T);
  h16* ph = vn;  // vn dead after k_tr
  hipLaunchKernelGGL(k_scan, dim3(32, 16), dim3(256), 0, stream, T, ph);
  h16* oh = (h16*)T;  // T dead after k_scan
  hipLaunchKernelGGL(k_att, dim3(64, 32), dim3(256), 0, stream, qn, kn, fc, vt, ph, oh);
  h16* an = xh;  // xh dead after k_qkv
  hipLaunchKernelGGL(k_rms, dim3(16384), dim3(256), 0, stream, oh, rw, an);
  hipLaunchKernelGGL(k_out, dim3(64, 4), dim3(512), 131072, stream, an, woh, out);
}